// Round 3
// baseline (1196.061 us; speedup 1.0000x reference)
//
#include <hip/hip_runtime.h>
#include <hip/hip_bf16.h>

#define NN 10000
#define EE 60000
#define HIDD 128
#define NH 8
#define INNERD 1024
#define FFD 512

using u16 = unsigned short;
using u32 = unsigned int;

__device__ __forceinline__ float u2f(u32 u) { return __uint_as_float(u << 16); }
__device__ __forceinline__ u16 f2b(float f) {
  __hip_bfloat16 b = __float2bfloat16(f);
  return *reinterpret_cast<u16*>(&b);
}
__device__ __forceinline__ float gelu_f(float x) {
  return 0.5f * x * (1.0f + erff(x * 0.70710678118654752f));
}
__device__ __forceinline__ u32 encMax(float f) {
  u32 b = __float_as_uint(f);
  return (b & 0x80000000u) ? ~b : (b | 0x80000000u);
}
__device__ __forceinline__ float decMax(u32 u) {
  u32 b = (u & 0x80000000u) ? (u & 0x7FFFFFFFu) : ~u;
  return __uint_as_float(b);
}

// ---------------- dtype detect: low u16 of each u32 word decoded as bf16.
// bf16 world: genuine values, |v| small. f32 world: random mantissa bits -> wild.
__global__ void detect_k(const u32* __restrict__ xw, int* __restrict__ flag) {
  if (threadIdx.x == 0 && blockIdx.x == 0) {
    int wild = 0;
    for (int i = 0; i < 256; ++i) {
      float v = u2f(xw[i] & 0xffffu);
      if (!(fabsf(v) < 1e4f)) ++wild;  // catches NaN too
    }
    *flag = (wild > 16) ? 1 : 0;  // 1 = inputs are f32
  }
}

#define NCVT 40
struct CvtArgs { const void* src[NCVT]; int cnt[NCVT]; int ntot; };

__global__ __launch_bounds__(256) void convert_k(CvtArgs a, const int* __restrict__ flag,
                                                 float* __restrict__ dst) {
  const int i = blockIdx.x * 256 + threadIdx.x;
  if (i >= a.ntot) return;
  int t = 0, off = i;
  while (off >= a.cnt[t]) { off -= a.cnt[t]; ++t; }
  const float v = (*flag) ? ((const float*)a.src[t])[off]
                          : u2f(((const u16*)a.src[t])[off]);
  dst[i] = v;
}

// ---------------- embed: h = x @ Win + bin + te + pos  (M=NN, K=64, N=128)
__global__ __launch_bounds__(128) void embed_k(
    const void* __restrict__ x, const float* __restrict__ Win,
    const float* __restrict__ bin, const float* __restrict__ te,
    const void* __restrict__ pos, const int* __restrict__ flag, float* __restrict__ h) {
  __shared__ float Ws[64][128];
  __shared__ float xs[16][64];
  const int f32in = *flag;
  const int j = threadIdx.x;           // 0..127 (output col)
  const int base = blockIdx.x * 16;    // 16 rows per block
  for (int i = 0; i < 64; ++i) Ws[i][j] = Win[i * 128 + j];
  for (int r = 0; r < 8; ++r) {
    int idx = r * 128 + j;             // 0..1023
    int row = idx >> 6, k = idx & 63;
    size_t gi = (size_t)(base + row) * 64 + k;
    xs[row][k] = f32in ? ((const float*)x)[gi] : u2f(((const u16*)x)[gi]);
  }
  __syncthreads();
  float bj = bin[j] + te[j];
  for (int row = 0; row < 16; ++row) {
    size_t gi = (size_t)(base + row) * 128 + j;
    float pv = f32in ? ((const float*)pos)[gi] : u2f(((const u16*)pos)[gi]);
    float acc = bj + pv;
#pragma unroll
    for (int k = 0; k < 64; ++k) acc += xs[row][k] * Ws[k][j];
    h[(size_t)(base + row) * 128 + j] = acc;
  }
}

// ---------------- generic GEMM: C[M,N] = A[M,K](f32) @ B[K,N](f32) + bias
// ACT: 0 none, 1 exact gelu.
// OUTB: 0 f32 out, 1 bf16 out, 2 runtime flag (1->f32 via Cf, 0->bf16 via Cb)
// ADDS: += add[M,N] (pre-store)
template <int ACT, int OUTB, int ADDS>
__global__ __launch_bounds__(256) void gemm_k(
    const float* __restrict__ A, const float* __restrict__ B,
    const float* __restrict__ bias, const float* __restrict__ add,
    float* __restrict__ Cf, u16* __restrict__ Cb, const int* __restrict__ oflag,
    int M, int N, int K) {
  __shared__ __align__(16) float As[16][64];  // [k][m]
  __shared__ __align__(16) float Bs[16][64];  // [k][n]
  const int t = threadIdx.x;
  const int tx = t & 15, ty = t >> 4;
  const int bm = blockIdx.y * 64, bn = blockIdx.x * 64;
  float c[4][4] = {{0.f}};
  const int am = t >> 2;            // 0..63 (tile row)
  const int ak = (t & 3) << 2;      // 0,4,8,12
  const int bk = t >> 4;            // 0..15
  const int bn4 = (t & 15) << 2;    // 0..60
  for (int k0 = 0; k0 < K; k0 += 16) {
    float4 av = make_float4(0.f, 0.f, 0.f, 0.f);
    const int arow = bm + am;
    if (arow < M) av = *reinterpret_cast<const float4*>(A + (size_t)arow * K + k0 + ak);
    As[ak + 0][am] = av.x; As[ak + 1][am] = av.y;
    As[ak + 2][am] = av.z; As[ak + 3][am] = av.w;
    float4 bv = *reinterpret_cast<const float4*>(B + (size_t)(k0 + bk) * N + bn + bn4);
    Bs[bk][bn4 + 0] = bv.x; Bs[bk][bn4 + 1] = bv.y;
    Bs[bk][bn4 + 2] = bv.z; Bs[bk][bn4 + 3] = bv.w;
    __syncthreads();
#pragma unroll
    for (int kk = 0; kk < 16; ++kk) {
      float4 a = *reinterpret_cast<const float4*>(&As[kk][ty << 2]);
      float4 b = *reinterpret_cast<const float4*>(&Bs[kk][tx << 2]);
      c[0][0] += a.x * b.x; c[0][1] += a.x * b.y; c[0][2] += a.x * b.z; c[0][3] += a.x * b.w;
      c[1][0] += a.y * b.x; c[1][1] += a.y * b.y; c[1][2] += a.y * b.z; c[1][3] += a.y * b.w;
      c[2][0] += a.z * b.x; c[2][1] += a.z * b.y; c[2][2] += a.z * b.z; c[2][3] += a.z * b.w;
      c[3][0] += a.w * b.x; c[3][1] += a.w * b.y; c[3][2] += a.w * b.z; c[3][3] += a.w * b.w;
    }
    __syncthreads();
  }
  const int f32out = (OUTB == 2) ? *oflag : 0;
#pragma unroll
  for (int i = 0; i < 4; ++i) {
    const int row = bm + (ty << 2) + i;
    if (row >= M) continue;
#pragma unroll
    for (int j = 0; j < 4; ++j) {
      const int col = bn + (tx << 2) + j;
      float v = c[i][j] + bias[col];
      if (ACT == 1) v = gelu_f(v);
      if (ADDS) v += add[(size_t)row * N + col];
      if (OUTB == 0)      Cf[(size_t)row * N + col] = v;
      else if (OUTB == 1) Cb[(size_t)row * N + col] = f2b(v);
      else {
        if (f32out) Cf[(size_t)row * N + col] = v;
        else        Cb[(size_t)row * N + col] = f2b(v);
      }
    }
  }
}

// ---------------- edge logits + segment max (one wave per edge, 8 heads x 8 lanes)
__global__ __launch_bounds__(256) void logits_k(
    const u16* __restrict__ q, const u16* __restrict__ kb,
    const int* __restrict__ ei, float* __restrict__ logits, u32* __restrict__ mEnc) {
  const int e = (blockIdx.x * blockDim.x + threadIdx.x) >> 6;
  if (e >= EE) return;
  const int lane = threadIdx.x & 63;
  const int h = lane >> 3, tt = lane & 7;
  const int s = ei[e], d = ei[EE + e];
  const u16* qp = q + (size_t)d * INNERD + h * 128 + tt * 16;
  const u16* kp = kb + (size_t)s * INNERD + h * 128 + tt * 16;
  float acc = 0.f;
#pragma unroll
  for (int half = 0; half < 2; ++half) {
    uint4 qv = *reinterpret_cast<const uint4*>(qp + half * 8);
    uint4 kv = *reinterpret_cast<const uint4*>(kp + half * 8);
    const u32 qa[4] = {qv.x, qv.y, qv.z, qv.w};
    const u32 ka[4] = {kv.x, kv.y, kv.z, kv.w};
#pragma unroll
    for (int i = 0; i < 4; ++i) {
      acc += u2f(qa[i] & 0xffffu) * u2f(ka[i] & 0xffffu);
      acc += u2f(qa[i] >> 16) * u2f(ka[i] >> 16);
    }
  }
  acc += __shfl_xor(acc, 1);
  acc += __shfl_xor(acc, 2);
  acc += __shfl_xor(acc, 4);
  if (tt == 0) {
    const float lg = acc * 0.088388347648318447f;  // 1/sqrt(128)
    logits[(size_t)e * NH + h] = lg;
    atomicMax(&mEnc[d * NH + h], encMax(lg));
  }
}

// ---------------- ex = exp(l - m), den += ex
__global__ __launch_bounds__(256) void exden_k(
    const float* __restrict__ logits, const u32* __restrict__ mEnc,
    const int* __restrict__ ei, float* __restrict__ ex, float* __restrict__ den) {
  const int i = blockIdx.x * blockDim.x + threadIdx.x;
  if (i >= EE * NH) return;
  const int e = i >> 3, h = i & 7;
  const int d = ei[EE + e];
  const float m = decMax(mEnc[d * NH + h]);
  const float v = expf(logits[i] - m);
  ex[i] = v;
  atomicAdd(&den[d * NH + h], v);
}

// ---------------- aggregation: agg[dst,:] += mean_h alpha*v[src,h,:] (wave/edge)
__global__ __launch_bounds__(256) void agg_k(
    const float* __restrict__ ex, const float* __restrict__ den,
    const u16* __restrict__ v, const int* __restrict__ ei, float* __restrict__ agg) {
  const int e = (blockIdx.x * blockDim.x + threadIdx.x) >> 6;
  if (e >= EE) return;
  const int lane = threadIdx.x & 63;
  const int s = ei[e], d = ei[EE + e];
  float a0 = 0.f, a1 = 0.f;
#pragma unroll
  for (int h = 0; h < NH; ++h) {
    const float alpha = ex[(size_t)e * NH + h] / (den[d * NH + h] + 1e-16f);
    a0 += alpha * u2f(v[(size_t)s * INNERD + h * 128 + lane]);
    a1 += alpha * u2f(v[(size_t)s * INNERD + h * 128 + 64 + lane]);
  }
  atomicAdd(&agg[(size_t)d * HIDD + lane], a0 * 0.125f);
  atomicAdd(&agg[(size_t)d * HIDD + 64 + lane], a1 * 0.125f);
}

// ---------------- beta gate + skip (wave per node)
__global__ __launch_bounds__(256) void beta_k(
    const float* __restrict__ agg, const float* __restrict__ xr,
    const float* __restrict__ Wb, float* __restrict__ outn) {
  const int n = (blockIdx.x * blockDim.x + threadIdx.x) >> 6;
  if (n >= NN) return;
  const int lane = threadIdx.x & 63;
  const float o0 = agg[(size_t)n * HIDD + lane], o1 = agg[(size_t)n * HIDD + 64 + lane];
  const float x0 = xr[(size_t)n * HIDD + lane], x1 = xr[(size_t)n * HIDD + 64 + lane];
  float s = o0 * Wb[lane] + o1 * Wb[64 + lane]
          + x0 * Wb[128 + lane] + x1 * Wb[192 + lane]
          + (o0 - x0) * Wb[256 + lane] + (o1 - x1) * Wb[320 + lane];
#pragma unroll
  for (int mask = 1; mask < 64; mask <<= 1) s += __shfl_xor(s, mask);
  const float beta = 1.f / (1.f + expf(-s));
  outn[(size_t)n * HIDD + lane]      = beta * x0 + (1.f - beta) * o0;
  outn[(size_t)n * HIDD + 64 + lane] = beta * x1 + (1.f - beta) * o1;
}

// ---------------- layernorm of (h + new) (wave per node)
__global__ __launch_bounds__(256) void ln_k(
    const float* __restrict__ h, const float* __restrict__ nw,
    const float* __restrict__ g, const float* __restrict__ b, float* __restrict__ r) {
  const int n = (blockIdx.x * blockDim.x + threadIdx.x) >> 6;
  if (n >= NN) return;
  const int lane = threadIdx.x & 63;
  const float v0 = h[(size_t)n * HIDD + lane] + nw[(size_t)n * HIDD + lane];
  const float v1 = h[(size_t)n * HIDD + 64 + lane] + nw[(size_t)n * HIDD + 64 + lane];
  float s = v0 + v1;
#pragma unroll
  for (int mask = 1; mask < 64; mask <<= 1) s += __shfl_xor(s, mask);
  const float mu = s * (1.f / 128.f);
  const float d0 = v0 - mu, d1 = v1 - mu;
  float vs = d0 * d0 + d1 * d1;
#pragma unroll
  for (int mask = 1; mask < 64; mask <<= 1) vs += __shfl_xor(vs, mask);
  const float rstd = rsqrtf(vs * (1.f / 128.f) + 1e-5f);
  r[(size_t)n * HIDD + lane]      = d0 * rstd * g[lane] + b[lane];
  r[(size_t)n * HIDD + 64 + lane] = d1 * rstd * g[64 + lane] + b[64 + lane];
}

extern "C" void kernel_launch(void* const* d_in, const int* in_sizes, int n_in,
                              void* d_out, int out_size, void* d_ws, size_t ws_size,
                              hipStream_t stream) {
  // ---- workspace carve ----
  char* w = (char*)d_ws;
  auto carve = [&](size_t bytes) { void* p = (void*)w; w += (bytes + 255) & ~(size_t)255; return p; };
  float* h_b[2];   h_b[0] = (float*)carve((size_t)NN * HIDD * 4); h_b[1] = (float*)carve((size_t)NN * HIDD * 4);
  float* new_b[2]; new_b[0] = (float*)carve((size_t)NN * HIDD * 4); new_b[1] = (float*)carve((size_t)NN * HIDD * 4);
  float* rbuf = (float*)carve((size_t)NN * HIDD * 4);
  float* mid  = (float*)carve((size_t)NN * FFD * 4);
  float* aggb = (float*)carve((size_t)NN * HIDD * 4);
  float* xrb  = (float*)carve((size_t)NN * HIDD * 4);
  u16* qb  = (u16*)carve((size_t)NN * INNERD * 2);   // bf16
  u16* kvb = (u16*)carve((size_t)NN * INNERD * 2);   // bf16 (k then reused for v)
  float* logitsb = (float*)carve((size_t)EE * NH * 4);
  float* exb     = (float*)carve((size_t)EE * NH * 4);
  float* denb    = (float*)carve((size_t)NN * NH * 4);
  u32* mEnc      = (u32*)carve((size_t)NN * NH * 4);
  int* flagp     = (int*)carve(256);
  // converted f32 weights region
  const int totCvt = 2 * 288896 + 2 * 826368;  // 2,230,528
  float* wf = (float*)carve((size_t)totCvt * 4);

  // ---- build conversion table + assign converted pointers ----
  CvtArgs ca; int nc = 0; int cum = 0;
  auto addc = [&](int inIdx, int n) -> float* {
    ca.src[nc] = d_in[inIdx]; ca.cnt[nc] = n; float* p = wf + cum; cum += n; ++nc; return p;
  };
  const float *WinF[2], *binF[2], *teF[2], *lngF[2], *lnbF[2], *W1F[2], *b1F[2],
      *W2F[2], *b2F[2], *WoutF[2], *boutF[2];
  const void* x_p[2]; const void* pos_p[2];
  for (int t = 0; t < 2; ++t) {
    const int o = t * 13;
    x_p[t] = d_in[o + 0];
    WinF[t] = addc(o + 1, 64 * HIDD);
    binF[t] = addc(o + 2, HIDD);
    pos_p[t] = d_in[o + 3];
    teF[t]  = addc(o + 4, HIDD);
    lngF[t] = addc(o + 5, 2 * HIDD);
    lnbF[t] = addc(o + 6, 2 * HIDD);
    W1F[t]  = addc(o + 7, 2 * HIDD * FFD);
    b1F[t]  = addc(o + 8, 2 * FFD);
    W2F[t]  = addc(o + 9, 2 * FFD * HIDD);
    b2F[t]  = addc(o + 10, 2 * HIDD);
    WoutF[t] = addc(o + 11, HIDD * HIDD);
    boutF[t] = addc(o + 12, HIDD);
  }
  const float *WqF[2], *WkF[2], *WvF[2], *WsF[2], *WbF[2], *bqF[2], *bkF[2], *bvF[2], *bsF[2];
  const int* ei_e[2];
  for (int et = 0; et < 2; ++et) {
    const int o = 26 + et * 10;
    WqF[et] = addc(o + 0, 2 * HIDD * INNERD);
    WkF[et] = addc(o + 1, 2 * HIDD * INNERD);
    WvF[et] = addc(o + 2, 2 * HIDD * INNERD);
    WsF[et] = addc(o + 3, 2 * HIDD * HIDD);
    WbF[et] = addc(o + 4, 2 * 384);
    bqF[et] = addc(o + 5, 2 * INNERD);
    bkF[et] = addc(o + 6, 2 * INNERD);
    bvF[et] = addc(o + 7, 2 * INNERD);
    bsF[et] = addc(o + 8, 2 * HIDD);
    ei_e[et] = (const int*)d_in[o + 9];
  }
  ca.ntot = cum;  // == totCvt

  const dim3 blk(256);
  const int MB = (NN + 63) / 64;  // 157

  // ---- dtype detect + convert ----
  detect_k<<<1, 64, 0, stream>>>((const u32*)d_in[0], flagp);
  convert_k<<<(cum + 255) / 256, blk, 0, stream>>>(ca, flagp, wf);

  auto tconv = [&](int l, int et, const float* hsrc, const float* hdst, float* outn) {
    const dim3 gq(INNERD / 64, MB);
    gemm_k<0, 1, 0><<<gq, blk, 0, stream>>>(hdst, WqF[et] + (size_t)l * HIDD * INNERD,
        bqF[et] + l * INNERD, nullptr, nullptr, qb, nullptr, NN, INNERD, HIDD);
    gemm_k<0, 1, 0><<<gq, blk, 0, stream>>>(hsrc, WkF[et] + (size_t)l * HIDD * INNERD,
        bkF[et] + l * INNERD, nullptr, nullptr, kvb, nullptr, NN, INNERD, HIDD);
    hipMemsetAsync(mEnc, 0, (size_t)NN * NH * 4, stream);
    hipMemsetAsync(denb, 0, (size_t)NN * NH * 4, stream);
    hipMemsetAsync(aggb, 0, (size_t)NN * HIDD * 4, stream);
    logits_k<<<(EE * 64) / 256, blk, 0, stream>>>(qb, kvb, ei_e[et], logitsb, mEnc);
    exden_k<<<(EE * NH + 255) / 256, blk, 0, stream>>>(logitsb, mEnc, ei_e[et], exb, denb);
    gemm_k<0, 1, 0><<<gq, blk, 0, stream>>>(hsrc, WvF[et] + (size_t)l * HIDD * INNERD,
        bvF[et] + l * INNERD, nullptr, nullptr, kvb, nullptr, NN, INNERD, HIDD);
    agg_k<<<(EE * 64) / 256, blk, 0, stream>>>(exb, denb, kvb, ei_e[et], aggb);
    const dim3 gs(HIDD / 64, MB);
    gemm_k<0, 0, 0><<<gs, blk, 0, stream>>>(hdst, WsF[et] + (size_t)l * HIDD * HIDD,
        bsF[et] + l * HIDD, nullptr, xrb, nullptr, nullptr, NN, HIDD, HIDD);
    beta_k<<<(NN * 64) / 256, blk, 0, stream>>>(aggb, xrb, WbF[et] + l * 384, outn);
  };

  auto ffn = [&](int l, int t, float* hb, const float* nb) {
    ln_k<<<(NN * 64) / 256, blk, 0, stream>>>(hb, nb, lngF[t] + l * HIDD, lnbF[t] + l * HIDD, rbuf);
    const dim3 g1(FFD / 64, MB);
    gemm_k<1, 0, 0><<<g1, blk, 0, stream>>>(rbuf, W1F[t] + (size_t)l * HIDD * FFD,
        b1F[t] + l * FFD, nullptr, mid, nullptr, nullptr, NN, FFD, HIDD);
    const dim3 g2(HIDD / 64, MB);
    gemm_k<0, 0, 1><<<g2, blk, 0, stream>>>(mid, W2F[t] + (size_t)l * FFD * HIDD,
        b2F[t] + l * HIDD, rbuf, hb, nullptr, nullptr, NN, HIDD, FFD);
  };

  // ---- forward ----
  embed_k<<<NN / 16, 128, 0, stream>>>(x_p[0], WinF[0], binF[0], teF[0], pos_p[0], flagp, h_b[0]);
  embed_k<<<NN / 16, 128, 0, stream>>>(x_p[1], WinF[1], binF[1], teF[1], pos_p[1], flagp, h_b[1]);
  for (int l = 0; l < 2; ++l) {
    tconv(l, 0, h_b[0], h_b[1], new_b[1]);  // jm: src=job, dst=mach
    tconv(l, 1, h_b[1], h_b[0], new_b[0]);  // mj: src=mach, dst=job
    ffn(l, 0, h_b[0], new_b[0]);
    ffn(l, 1, h_b[1], new_b[1]);
  }
  // ---- output projections: dtype-hedged epilogue (f32 world -> f32) ----
  const dim3 go(HIDD / 64, MB);
  gemm_k<0, 2, 0><<<go, blk, 0, stream>>>(h_b[0], WoutF[0], boutF[0], nullptr,
      (float*)d_out, (u16*)d_out, flagp, NN, HIDD, HIDD);
  gemm_k<0, 2, 0><<<go, blk, 0, stream>>>(h_b[1], WoutF[1], boutF[1], nullptr,
      (float*)d_out + (size_t)NN * HIDD, (u16*)d_out + (size_t)NN * HIDD, flagp,
      NN, HIDD, HIDD);
}

// Round 4
// 808.813 us; speedup vs baseline: 1.4788x; 1.4788x over previous
//
#include <hip/hip_runtime.h>
#include <hip/hip_bf16.h>

#define NN 10000
#define EE 60000
#define HIDD 128
#define NH 8
#define INNERD 1024
#define FFD 512

using u16 = unsigned short;
using u32 = unsigned int;

typedef __bf16 bf16x8 __attribute__((ext_vector_type(8)));
typedef float f32x4 __attribute__((ext_vector_type(4)));

__device__ __forceinline__ float u2f(u32 u) { return __uint_as_float(u << 16); }
__device__ __forceinline__ u16 f2b(float f) {  // RNE
  u32 x = __float_as_uint(f);
  return (u16)((x + 0x7fffu + ((x >> 16) & 1u)) >> 16);
}
__device__ __forceinline__ float gelu_f(float x) {
  return 0.5f * x * (1.0f + erff(x * 0.70710678118654752f));
}
__device__ __forceinline__ u32 encMax(float f) {
  u32 b = __float_as_uint(f);
  return (b & 0x80000000u) ? ~b : (b | 0x80000000u);
}
__device__ __forceinline__ float decMax(u32 u) {
  u32 b = (u & 0x80000000u) ? (u & 0x7FFFFFFFu) : ~u;
  return __uint_as_float(b);
}

// ---------------- dtype detect (kept: runtime hedge, flag=1 means f32 inputs)
__global__ void detect_k(const u32* __restrict__ xw, int* __restrict__ flag) {
  if (threadIdx.x == 0 && blockIdx.x == 0) {
    int wild = 0;
    for (int i = 0; i < 256; ++i) {
      float v = u2f(xw[i] & 0xffffu);
      if (!(fabsf(v) < 1e4f)) ++wild;
    }
    *flag = (wild > 16) ? 1 : 0;
  }
}

#define NCVT 30
struct CvtArgs { const void* src[NCVT]; int cnt[NCVT]; int ntot; };

__global__ __launch_bounds__(256) void convert_k(CvtArgs a, const int* __restrict__ flag,
                                                 float* __restrict__ dst) {
  const int i = blockIdx.x * 256 + threadIdx.x;
  if (i >= a.ntot) return;
  int t = 0, off = i;
  while (off >= a.cnt[t]) { off -= a.cnt[t]; ++t; }
  const float v = (*flag) ? ((const float*)a.src[t])[off]
                          : u2f(((const u16*)a.src[t])[off]);
  dst[i] = v;
}

// ---------------- batched weight transpose: W[K][N] (f32 or bf16 per flag) -> WT bf16 [N][K]
struct TT { const void* s; long off; u16* d; int K; int N; };
struct TTab { TT m[20]; };

__global__ __launch_bounds__(256) void transT_k(TTab tt, const int* __restrict__ flag) {
  const TT m = tt.m[blockIdx.z];
  const int n0 = blockIdx.x * 32, k0 = blockIdx.y * 32;
  if (n0 >= m.N || k0 >= m.K) return;
  __shared__ float tile[32][33];
  const int c = threadIdx.x;  // 0..31
  const int f32in = *flag;
  for (int i = threadIdx.y; i < 32; i += 8) {
    const long gi = m.off + (long)(k0 + i) * m.N + n0 + c;
    tile[i][c] = f32in ? ((const float*)m.s)[gi] : u2f(((const u16*)m.s)[gi]);
  }
  __syncthreads();
  for (int i = threadIdx.y; i < 32; i += 8)
    m.d[(size_t)(n0 + i) * m.K + k0 + c] = f2b(tile[c][i]);
}

// ---------------- embed: h = x @ Win + bin + te + pos  (M=NN, K=64, N=128)
__global__ __launch_bounds__(128) void embed_k(
    const void* __restrict__ x, const float* __restrict__ Win,
    const float* __restrict__ bin, const float* __restrict__ te,
    const void* __restrict__ pos, const int* __restrict__ flag, float* __restrict__ h) {
  __shared__ float Ws[64][128];
  __shared__ float xs[16][64];
  const int f32in = *flag;
  const int j = threadIdx.x;
  const int base = blockIdx.x * 16;
  for (int i = 0; i < 64; ++i) Ws[i][j] = Win[i * 128 + j];
  for (int r = 0; r < 8; ++r) {
    int idx = r * 128 + j;
    int row = idx >> 6, k = idx & 63;
    size_t gi = (size_t)(base + row) * 64 + k;
    xs[row][k] = f32in ? ((const float*)x)[gi] : u2f(((const u16*)x)[gi]);
  }
  __syncthreads();
  float bj = bin[j] + te[j];
  for (int row = 0; row < 16; ++row) {
    size_t gi = (size_t)(base + row) * 128 + j;
    float pv = f32in ? ((const float*)pos)[gi] : u2f(((const u16*)pos)[gi]);
    float acc = bj + pv;
#pragma unroll
    for (int k = 0; k < 64; ++k) acc += xs[row][k] * Ws[k][j];
    h[(size_t)(base + row) * 128 + j] = acc;
  }
}

// ---------------- MFMA GEMM: C[M,N] = A[M,K]_f32 @ W  (W given as WT bf16 [N][K])
// BM=128, BN=64, BK=32; 256 threads = 4 waves; wave owns 32 rows; acc[2][4] of 16x16.
// ACT: 1 = exact gelu.  OUTB: 0 f32, 1 bf16.  ADDS: += add[M,N] pre-store.
template <int ACT, int OUTB, int ADDS>
__global__ __launch_bounds__(256) void mgemm_k(
    const float* __restrict__ A, const u16* __restrict__ WT,
    const float* __restrict__ bias, const float* __restrict__ add,
    float* __restrict__ Cf, u16* __restrict__ Cb, int M, int N, int K) {
  __shared__ __align__(16) u16 Asl[128][40];  // pad: 80B rows (16B-aligned, low conflict)
  __shared__ __align__(16) u16 Bsl[64][40];
  const int t = threadIdx.x;
  const int lane = t & 63, wid = t >> 6;
  const int bm = blockIdx.y * 128, bn = blockIdx.x * 64;
  const int rg = lane >> 4, rr = lane & 15;
  f32x4 acc[2][4];
#pragma unroll
  for (int i = 0; i < 2; ++i)
#pragma unroll
    for (int j = 0; j < 4; ++j) acc[i][j] = (f32x4){0.f, 0.f, 0.f, 0.f};
  const int ar = t >> 1;            // 0..127 A row
  const int ah = (t & 1) << 4;      // 0/16 A k-offset
  const int wr = t >> 2;            // 0..63 WT row (=out col)
  const int wk = (t & 3) << 3;      // 0,8,16,24

  for (int k0 = 0; k0 < K; k0 += 32) {
    // ---- stage A (f32 -> bf16) ----
    const int garow = bm + ar;
    float4 v0 = {0,0,0,0}, v1 = {0,0,0,0}, v2 = {0,0,0,0}, v3 = {0,0,0,0};
    if (garow < M) {
      const float* ap = A + (size_t)garow * K + k0 + ah;
      v0 = *reinterpret_cast<const float4*>(ap);
      v1 = *reinterpret_cast<const float4*>(ap + 4);
      v2 = *reinterpret_cast<const float4*>(ap + 8);
      v3 = *reinterpret_cast<const float4*>(ap + 12);
    }
    u32 pk[8];
    pk[0] = (u32)f2b(v0.x) | ((u32)f2b(v0.y) << 16);
    pk[1] = (u32)f2b(v0.z) | ((u32)f2b(v0.w) << 16);
    pk[2] = (u32)f2b(v1.x) | ((u32)f2b(v1.y) << 16);
    pk[3] = (u32)f2b(v1.z) | ((u32)f2b(v1.w) << 16);
    pk[4] = (u32)f2b(v2.x) | ((u32)f2b(v2.y) << 16);
    pk[5] = (u32)f2b(v2.z) | ((u32)f2b(v2.w) << 16);
    pk[6] = (u32)f2b(v3.x) | ((u32)f2b(v3.y) << 16);
    pk[7] = (u32)f2b(v3.z) | ((u32)f2b(v3.w) << 16);
    uint4 lo = {pk[0], pk[1], pk[2], pk[3]}, hi = {pk[4], pk[5], pk[6], pk[7]};
    *reinterpret_cast<uint4*>(&Asl[ar][ah]) = lo;
    *reinterpret_cast<uint4*>(&Asl[ar][ah + 8]) = hi;
    // ---- stage B (bf16 WT rows) ----
    const uint4 bv = *reinterpret_cast<const uint4*>(WT + (size_t)(bn + wr) * K + k0 + wk);
    *reinterpret_cast<uint4*>(&Bsl[wr][wk]) = bv;
    __syncthreads();
    // ---- fragments + MFMA ----
    bf16x8 af[2], bfr[4];
#pragma unroll
    for (int mi = 0; mi < 2; ++mi)
      af[mi] = *reinterpret_cast<const bf16x8*>(&Asl[wid * 32 + mi * 16 + rr][rg * 8]);
#pragma unroll
    for (int ni = 0; ni < 4; ++ni)
      bfr[ni] = *reinterpret_cast<const bf16x8*>(&Bsl[ni * 16 + rr][rg * 8]);
#pragma unroll
    for (int mi = 0; mi < 2; ++mi)
#pragma unroll
      for (int ni = 0; ni < 4; ++ni)
        acc[mi][ni] = __builtin_amdgcn_mfma_f32_16x16x32_bf16(af[mi], bfr[ni], acc[mi][ni], 0, 0, 0);
    __syncthreads();
  }
  // ---- epilogue ----
#pragma unroll
  for (int mi = 0; mi < 2; ++mi) {
#pragma unroll
    for (int ni = 0; ni < 4; ++ni) {
      const int col = bn + ni * 16 + rr;
      const float bcol = bias[col];
#pragma unroll
      for (int r = 0; r < 4; ++r) {
        const int row = bm + wid * 32 + mi * 16 + rg * 4 + r;
        if (row >= M) continue;
        float v = acc[mi][ni][r] + bcol;
        if (ACT == 1) v = gelu_f(v);
        if (ADDS) v += add[(size_t)row * N + col];
        if (OUTB) Cb[(size_t)row * N + col] = f2b(v);
        else      Cf[(size_t)row * N + col] = v;
      }
    }
  }
}

// ---------------- legacy fp32 vector GEMM (kept for Ws + Wout: precision hedge)
template <int ACT, int OUTB, int ADDS>
__global__ __launch_bounds__(256) void gemm_k(
    const float* __restrict__ A, const float* __restrict__ B,
    const float* __restrict__ bias, const float* __restrict__ add,
    float* __restrict__ Cf, u16* __restrict__ Cb, const int* __restrict__ oflag,
    int M, int N, int K) {
  __shared__ __align__(16) float As[16][64];
  __shared__ __align__(16) float Bs[16][64];
  const int t = threadIdx.x;
  const int tx = t & 15, ty = t >> 4;
  const int bm = blockIdx.y * 64, bn = blockIdx.x * 64;
  float c[4][4] = {{0.f}};
  const int am = t >> 2;
  const int ak = (t & 3) << 2;
  const int bk = t >> 4;
  const int bn4 = (t & 15) << 2;
  for (int k0 = 0; k0 < K; k0 += 16) {
    float4 av = make_float4(0.f, 0.f, 0.f, 0.f);
    const int arow = bm + am;
    if (arow < M) av = *reinterpret_cast<const float4*>(A + (size_t)arow * K + k0 + ak);
    As[ak + 0][am] = av.x; As[ak + 1][am] = av.y;
    As[ak + 2][am] = av.z; As[ak + 3][am] = av.w;
    float4 bv = *reinterpret_cast<const float4*>(B + (size_t)(k0 + bk) * N + bn + bn4);
    Bs[bk][bn4 + 0] = bv.x; Bs[bk][bn4 + 1] = bv.y;
    Bs[bk][bn4 + 2] = bv.z; Bs[bk][bn4 + 3] = bv.w;
    __syncthreads();
#pragma unroll
    for (int kk = 0; kk < 16; ++kk) {
      float4 a = *reinterpret_cast<const float4*>(&As[kk][ty << 2]);
      float4 b = *reinterpret_cast<const float4*>(&Bs[kk][tx << 2]);
      c[0][0] += a.x * b.x; c[0][1] += a.x * b.y; c[0][2] += a.x * b.z; c[0][3] += a.x * b.w;
      c[1][0] += a.y * b.x; c[1][1] += a.y * b.y; c[1][2] += a.y * b.z; c[1][3] += a.y * b.w;
      c[2][0] += a.z * b.x; c[2][1] += a.z * b.y; c[2][2] += a.z * b.z; c[2][3] += a.z * b.w;
      c[3][0] += a.w * b.x; c[3][1] += a.w * b.y; c[3][2] += a.w * b.z; c[3][3] += a.w * b.w;
    }
    __syncthreads();
  }
  const int f32out = (OUTB == 2) ? *oflag : 0;
#pragma unroll
  for (int i = 0; i < 4; ++i) {
    const int row = bm + (ty << 2) + i;
    if (row >= M) continue;
#pragma unroll
    for (int j = 0; j < 4; ++j) {
      const int col = bn + (tx << 2) + j;
      float v = c[i][j] + bias[col];
      if (ACT == 1) v = gelu_f(v);
      if (ADDS) v += add[(size_t)row * N + col];
      if (OUTB == 0)      Cf[(size_t)row * N + col] = v;
      else if (OUTB == 1) Cb[(size_t)row * N + col] = f2b(v);
      else {
        if (f32out) Cf[(size_t)row * N + col] = v;
        else        Cb[(size_t)row * N + col] = f2b(v);
      }
    }
  }
}

// ---------------- edge logits + segment max
__global__ __launch_bounds__(256) void logits_k(
    const u16* __restrict__ q, const u16* __restrict__ kb,
    const int* __restrict__ ei, float* __restrict__ logits, u32* __restrict__ mEnc) {
  const int e = (blockIdx.x * blockDim.x + threadIdx.x) >> 6;
  if (e >= EE) return;
  const int lane = threadIdx.x & 63;
  const int h = lane >> 3, tt = lane & 7;
  const int s = ei[e], d = ei[EE + e];
  const u16* qp = q + (size_t)d * INNERD + h * 128 + tt * 16;
  const u16* kp = kb + (size_t)s * INNERD + h * 128 + tt * 16;
  float acc = 0.f;
#pragma unroll
  for (int half = 0; half < 2; ++half) {
    uint4 qv = *reinterpret_cast<const uint4*>(qp + half * 8);
    uint4 kv = *reinterpret_cast<const uint4*>(kp + half * 8);
    const u32 qa[4] = {qv.x, qv.y, qv.z, qv.w};
    const u32 ka[4] = {kv.x, kv.y, kv.z, kv.w};
#pragma unroll
    for (int i = 0; i < 4; ++i) {
      acc += u2f(qa[i] & 0xffffu) * u2f(ka[i] & 0xffffu);
      acc += u2f(qa[i] >> 16) * u2f(ka[i] >> 16);
    }
  }
  acc += __shfl_xor(acc, 1);
  acc += __shfl_xor(acc, 2);
  acc += __shfl_xor(acc, 4);
  if (tt == 0) {
    const float lg = acc * 0.088388347648318447f;
    logits[(size_t)e * NH + h] = lg;
    atomicMax(&mEnc[d * NH + h], encMax(lg));
  }
}

__global__ __launch_bounds__(256) void exden_k(
    const float* __restrict__ logits, const u32* __restrict__ mEnc,
    const int* __restrict__ ei, float* __restrict__ ex, float* __restrict__ den) {
  const int i = blockIdx.x * blockDim.x + threadIdx.x;
  if (i >= EE * NH) return;
  const int e = i >> 3, h = i & 7;
  const int d = ei[EE + e];
  const float m = decMax(mEnc[d * NH + h]);
  const float v = expf(logits[i] - m);
  ex[i] = v;
  atomicAdd(&den[d * NH + h], v);
}

__global__ __launch_bounds__(256) void agg_k(
    const float* __restrict__ ex, const float* __restrict__ den,
    const u16* __restrict__ v, const int* __restrict__ ei, float* __restrict__ agg) {
  const int e = (blockIdx.x * blockDim.x + threadIdx.x) >> 6;
  if (e >= EE) return;
  const int lane = threadIdx.x & 63;
  const int s = ei[e], d = ei[EE + e];
  float a0 = 0.f, a1 = 0.f;
#pragma unroll
  for (int h = 0; h < NH; ++h) {
    const float alpha = ex[(size_t)e * NH + h] / (den[d * NH + h] + 1e-16f);
    a0 += alpha * u2f(v[(size_t)s * INNERD + h * 128 + lane]);
    a1 += alpha * u2f(v[(size_t)s * INNERD + h * 128 + 64 + lane]);
  }
  atomicAdd(&agg[(size_t)d * HIDD + lane], a0 * 0.125f);
  atomicAdd(&agg[(size_t)d * HIDD + 64 + lane], a1 * 0.125f);
}

__global__ __launch_bounds__(256) void beta_k(
    const float* __restrict__ agg, const float* __restrict__ xr,
    const float* __restrict__ Wb, float* __restrict__ outn) {
  const int n = (blockIdx.x * blockDim.x + threadIdx.x) >> 6;
  if (n >= NN) return;
  const int lane = threadIdx.x & 63;
  const float o0 = agg[(size_t)n * HIDD + lane], o1 = agg[(size_t)n * HIDD + 64 + lane];
  const float x0 = xr[(size_t)n * HIDD + lane], x1 = xr[(size_t)n * HIDD + 64 + lane];
  float s = o0 * Wb[lane] + o1 * Wb[64 + lane]
          + x0 * Wb[128 + lane] + x1 * Wb[192 + lane]
          + (o0 - x0) * Wb[256 + lane] + (o1 - x1) * Wb[320 + lane];
#pragma unroll
  for (int mask = 1; mask < 64; mask <<= 1) s += __shfl_xor(s, mask);
  const float beta = 1.f / (1.f + expf(-s));
  outn[(size_t)n * HIDD + lane]      = beta * x0 + (1.f - beta) * o0;
  outn[(size_t)n * HIDD + 64 + lane] = beta * x1 + (1.f - beta) * o1;
}

__global__ __launch_bounds__(256) void ln_k(
    const float* __restrict__ h, const float* __restrict__ nw,
    const float* __restrict__ g, const float* __restrict__ b, float* __restrict__ r) {
  const int n = (blockIdx.x * blockDim.x + threadIdx.x) >> 6;
  if (n >= NN) return;
  const int lane = threadIdx.x & 63;
  const float v0 = h[(size_t)n * HIDD + lane] + nw[(size_t)n * HIDD + lane];
  const float v1 = h[(size_t)n * HIDD + 64 + lane] + nw[(size_t)n * HIDD + 64 + lane];
  float s = v0 + v1;
#pragma unroll
  for (int mask = 1; mask < 64; mask <<= 1) s += __shfl_xor(s, mask);
  const float mu = s * (1.f / 128.f);
  const float d0 = v0 - mu, d1 = v1 - mu;
  float vs = d0 * d0 + d1 * d1;
#pragma unroll
  for (int mask = 1; mask < 64; mask <<= 1) vs += __shfl_xor(vs, mask);
  const float rstd = rsqrtf(vs * (1.f / 128.f) + 1e-5f);
  r[(size_t)n * HIDD + lane]      = d0 * rstd * g[lane] + b[lane];
  r[(size_t)n * HIDD + 64 + lane] = d1 * rstd * g[64 + lane] + b[64 + lane];
}

extern "C" void kernel_launch(void* const* d_in, const int* in_sizes, int n_in,
                              void* d_out, int out_size, void* d_ws, size_t ws_size,
                              hipStream_t stream) {
  char* w = (char*)d_ws;
  auto carve = [&](size_t bytes) { void* p = (void*)w; w += (bytes + 255) & ~(size_t)255; return p; };
  float* h_b[2];   h_b[0] = (float*)carve((size_t)NN * HIDD * 4); h_b[1] = (float*)carve((size_t)NN * HIDD * 4);
  float* new_b[2]; new_b[0] = (float*)carve((size_t)NN * HIDD * 4); new_b[1] = (float*)carve((size_t)NN * HIDD * 4);
  float* rbuf = (float*)carve((size_t)NN * HIDD * 4);
  float* mid  = (float*)carve((size_t)NN * FFD * 4);
  float* aggb = (float*)carve((size_t)NN * HIDD * 4);
  float* xrb  = (float*)carve((size_t)NN * HIDD * 4);
  u16* qb  = (u16*)carve((size_t)NN * INNERD * 2);
  u16* kvb = (u16*)carve((size_t)NN * INNERD * 2);
  float* logitsb = (float*)carve((size_t)EE * NH * 4);
  float* exb     = (float*)carve((size_t)EE * NH * 4);
  float* denb    = (float*)carve((size_t)NN * NH * 4);
  u32* mEnc      = (u32*)carve((size_t)NN * NH * 4);
  int* flagp     = (int*)carve(256);
  // small f32 params (biases, LN, Ws, Wout, Win, Wb)
  const int totCvt = 2 * 26752 + 2 * 39936;  // 133,376
  float* wf = (float*)carve((size_t)totCvt * 4);
  // transposed bf16 weights
  u16* wtp = (u16*)carve((size_t)2097152 * 2);

  // ---- f32 conversion table (small tensors only) ----
  CvtArgs ca; int nc = 0; int cum = 0;
  auto addc = [&](int inIdx, int n) -> float* {
    ca.src[nc] = d_in[inIdx]; ca.cnt[nc] = n; float* p = wf + cum; cum += n; ++nc; return p;
  };
  const float *WinF[2], *binF[2], *teF[2], *lngF[2], *lnbF[2], *b1F[2], *b2F[2], *WoutF[2], *boutF[2];
  const void* x_p[2]; const void* pos_p[2];
  for (int t = 0; t < 2; ++t) {
    const int o = t * 13;
    x_p[t] = d_in[o + 0];
    WinF[t] = addc(o + 1, 64 * HIDD);
    binF[t] = addc(o + 2, HIDD);
    pos_p[t] = d_in[o + 3];
    teF[t]  = addc(o + 4, HIDD);
    lngF[t] = addc(o + 5, 2 * HIDD);
    lnbF[t] = addc(o + 6, 2 * HIDD);
    b1F[t]  = addc(o + 8, 2 * FFD);
    b2F[t]  = addc(o + 10, 2 * HIDD);
    WoutF[t] = addc(o + 11, HIDD * HIDD);
    boutF[t] = addc(o + 12, HIDD);
  }
  const float *WsF[2], *WbF[2], *bqF[2], *bkF[2], *bvF[2], *bsF[2];
  const int* ei_e[2];
  for (int et = 0; et < 2; ++et) {
    const int o = 26 + et * 10;
    WsF[et] = addc(o + 3, 2 * HIDD * HIDD);
    WbF[et] = addc(o + 4, 2 * 384);
    bqF[et] = addc(o + 5, 2 * INNERD);
    bkF[et] = addc(o + 6, 2 * INNERD);
    bvF[et] = addc(o + 7, 2 * INNERD);
    bsF[et] = addc(o + 8, 2 * HIDD);
    ei_e[et] = (const int*)d_in[o + 9];
  }
  ca.ntot = cum;

  // ---- transpose table: Wq/Wk/Wv (12x [128][1024]), W1 (4x [128][512]), W2 (4x [512][128]) ----
  TTab tt; int ntt = 0; u16* tcur = wtp;
  auto addT = [&](const void* s, long off, int K, int N) -> u16* {
    tt.m[ntt] = {s, off, tcur, K, N}; u16* r = tcur; tcur += (size_t)K * N; ++ntt; return r;
  };
  u16 *WqT[2][2], *WkT[2][2], *WvT[2][2], *W1T[2][2], *W2T[2][2];
  for (int et = 0; et < 2; ++et) {
    const int o = 26 + et * 10;
    for (int l = 0; l < 2; ++l) {
      WqT[et][l] = addT(d_in[o + 0], (long)l * HIDD * INNERD, HIDD, INNERD);
      WkT[et][l] = addT(d_in[o + 1], (long)l * HIDD * INNERD, HIDD, INNERD);
      WvT[et][l] = addT(d_in[o + 2], (long)l * HIDD * INNERD, HIDD, INNERD);
    }
  }
  for (int t = 0; t < 2; ++t) {
    const int o = t * 13;
    for (int l = 0; l < 2; ++l) {
      W1T[t][l] = addT(d_in[o + 7], (long)l * HIDD * FFD, HIDD, FFD);
      W2T[t][l] = addT(d_in[o + 9], (long)l * FFD * HIDD, FFD, HIDD);
    }
  }

  const dim3 blk(256);
  const int MB64 = (NN + 63) / 64;     // 157 (legacy gemm)
  const int MB128 = (NN + 127) / 128;  // 79 (mfma gemm)

  // ---- prep ----
  detect_k<<<1, 64, 0, stream>>>((const u32*)d_in[0], flagp);
  convert_k<<<(cum + 255) / 256, blk, 0, stream>>>(ca, flagp, wf);
  transT_k<<<dim3(32, 16, 20), dim3(32, 8), 0, stream>>>(tt, flagp);

  auto tconv = [&](int l, int et, const float* hsrc, const float* hdst, float* outn) {
    const dim3 gq(INNERD / 64, MB128);
    mgemm_k<0, 1, 0><<<gq, blk, 0, stream>>>(hdst, WqT[et][l], bqF[et] + l * INNERD,
        nullptr, nullptr, qb, NN, INNERD, HIDD);
    mgemm_k<0, 1, 0><<<gq, blk, 0, stream>>>(hsrc, WkT[et][l], bkF[et] + l * INNERD,
        nullptr, nullptr, kvb, NN, INNERD, HIDD);
    hipMemsetAsync(mEnc, 0, (size_t)NN * NH * 4, stream);
    hipMemsetAsync(denb, 0, (size_t)NN * NH * 4, stream);
    hipMemsetAsync(aggb, 0, (size_t)NN * HIDD * 4, stream);
    logits_k<<<(EE * 64) / 256, blk, 0, stream>>>(qb, kvb, ei_e[et], logitsb, mEnc);
    exden_k<<<(EE * NH + 255) / 256, blk, 0, stream>>>(logitsb, mEnc, ei_e[et], exb, denb);
    mgemm_k<0, 1, 0><<<gq, blk, 0, stream>>>(hsrc, WvT[et][l], bvF[et] + l * INNERD,
        nullptr, nullptr, kvb, NN, INNERD, HIDD);
    agg_k<<<(EE * 64) / 256, blk, 0, stream>>>(exb, denb, kvb, ei_e[et], aggb);
    const dim3 gs(HIDD / 64, MB64);
    gemm_k<0, 0, 0><<<gs, blk, 0, stream>>>(hdst, WsF[et] + (size_t)l * HIDD * HIDD,
        bsF[et] + l * HIDD, nullptr, xrb, nullptr, nullptr, NN, HIDD, HIDD);
    beta_k<<<(NN * 64) / 256, blk, 0, stream>>>(aggb, xrb, WbF[et] + l * 384, outn);
  };

  auto ffn = [&](int l, int t, float* hb, const float* nb) {
    ln_k<<<(NN * 64) / 256, blk, 0, stream>>>(hb, nb, lngF[t] + l * HIDD, lnbF[t] + l * HIDD, rbuf);
    mgemm_k<1, 0, 0><<<dim3(FFD / 64, MB128), blk, 0, stream>>>(rbuf, W1T[t][l],
        b1F[t] + l * FFD, nullptr, mid, nullptr, NN, FFD, HIDD);
    mgemm_k<0, 0, 1><<<dim3(HIDD / 64, MB128), blk, 0, stream>>>(mid, W2T[t][l],
        b2F[t] + l * HIDD, rbuf, hb, nullptr, NN, HIDD, FFD);
  };

  // ---- forward ----
  embed_k<<<NN / 16, 128, 0, stream>>>(x_p[0], WinF[0], binF[0], teF[0], pos_p[0], flagp, h_b[0]);
  embed_k<<<NN / 16, 128, 0, stream>>>(x_p[1], WinF[1], binF[1], teF[1], pos_p[1], flagp, h_b[1]);
  for (int l = 0; l < 2; ++l) {
    tconv(l, 0, h_b[0], h_b[1], new_b[1]);
    tconv(l, 1, h_b[1], h_b[0], new_b[0]);
    ffn(l, 0, h_b[0], new_b[0]);
    ffn(l, 1, h_b[1], new_b[1]);
  }
  const dim3 go(HIDD / 64, MB64);
  gemm_k<0, 2, 0><<<go, blk, 0, stream>>>(h_b[0], WoutF[0], boutF[0], nullptr,
      (float*)d_out, (u16*)d_out, flagp, NN, HIDD, HIDD);
  gemm_k<0, 2, 0><<<go, blk, 0, stream>>>(h_b[1], WoutF[1], boutF[1], nullptr,
      (float*)d_out + (size_t)NN * HIDD, (u16*)d_out + (size_t)NN * HIDD, flagp,
      NN, HIDD, HIDD);
}

// Round 6
// 679.404 us; speedup vs baseline: 1.7605x; 1.1905x over previous
//
#include <hip/hip_runtime.h>
#include <hip/hip_bf16.h>

#define NN 10000
#define EE 60000
#define HIDD 128
#define NH 8
#define INNERD 1024
#define FFD 512
#define KVQ 3072

using u16 = unsigned short;
using u32 = unsigned int;

typedef __bf16 bf16x8 __attribute__((ext_vector_type(8)));
typedef float f32x4 __attribute__((ext_vector_type(4)));

__device__ __forceinline__ float u2f(u32 u) { return __uint_as_float(u << 16); }
__device__ __forceinline__ u16 f2b(float f) {  // RNE
  u32 x = __float_as_uint(f);
  return (u16)((x + 0x7fffu + ((x >> 16) & 1u)) >> 16);
}
__device__ __forceinline__ float gelu_f(float x) {
  return 0.5f * x * (1.0f + erff(x * 0.70710678118654752f));
}

// ---------------- dtype detect (runtime hedge, flag=1 means f32 inputs)
__global__ void detect_k(const u32* __restrict__ xw, int* __restrict__ flag) {
  if (threadIdx.x == 0 && blockIdx.x == 0) {
    int wild = 0;
    for (int i = 0; i < 256; ++i) {
      float v = u2f(xw[i] & 0xffffu);
      if (!(fabsf(v) < 1e4f)) ++wild;
    }
    *flag = (wild > 16) ? 1 : 0;
  }
}

#define NCVT 30
struct CvtArgs { const void* src[NCVT]; int cnt[NCVT]; int ntot; };

__global__ __launch_bounds__(256) void convert_k(CvtArgs a, const int* __restrict__ flag,
                                                 float* __restrict__ dst) {
  const int i = blockIdx.x * 256 + threadIdx.x;
  if (i >= a.ntot) return;
  int t = 0, off = i;
  while (off >= a.cnt[t]) { off -= a.cnt[t]; ++t; }
  const float v = (*flag) ? ((const float*)a.src[t])[off]
                          : u2f(((const u16*)a.src[t])[off]);
  dst[i] = v;
}

// ---------------- batched weight transpose: W[K][N] -> WT bf16 [N][K]
struct TT { const void* s; long off; u16* d; int K; int N; };
struct TTab { TT m[20]; };

__global__ __launch_bounds__(256) void transT_k(TTab tt, const int* __restrict__ flag) {
  const TT m = tt.m[blockIdx.z];
  const int n0 = blockIdx.x * 32, k0 = blockIdx.y * 32;
  if (n0 >= m.N || k0 >= m.K) return;
  __shared__ float tile[32][33];
  const int c = threadIdx.x;
  const int f32in = *flag;
  for (int i = threadIdx.y; i < 32; i += 8) {
    const long gi = m.off + (long)(k0 + i) * m.N + n0 + c;
    tile[i][c] = f32in ? ((const float*)m.s)[gi] : u2f(((const u16*)m.s)[gi]);
  }
  __syncthreads();
  for (int i = threadIdx.y; i < 32; i += 8)
    m.d[(size_t)(n0 + i) * m.K + k0 + c] = f2b(tile[c][i]);
}

// ---------------- CSR build
__global__ __launch_bounds__(256) void hist_k(const int* __restrict__ ei0,
                                              const int* __restrict__ ei1,
                                              int* __restrict__ hist) {
  const int e = blockIdx.x * 256 + threadIdx.x;
  if (e >= EE) return;
  const int et = blockIdx.y;
  const int* ei = et ? ei1 : ei0;
  atomicAdd(&hist[et * NN + ei[EE + e]], 1);
}

__global__ __launch_bounds__(256) void scan_k(const int* __restrict__ hist,
                                              int* __restrict__ rowptr,
                                              int* __restrict__ cursor) {
  const int et = blockIdx.x;
  const int* h = hist + et * NN;
  int* rp = rowptr + et * (NN + 1);
  int* cu = cursor + et * NN;
  __shared__ int buf[256];
  __shared__ int carry;
  const int t = threadIdx.x;
  if (t == 0) carry = 0;
  __syncthreads();
  for (int base = 0; base < NN; base += 256) {
    int v = (base + t < NN) ? h[base + t] : 0;
    buf[t] = v;
    __syncthreads();
    for (int off = 1; off < 256; off <<= 1) {
      int x = (t >= off) ? buf[t - off] : 0;
      __syncthreads();
      buf[t] += x;
      __syncthreads();
    }
    const int excl = buf[t] + carry - v;
    if (base + t < NN) { rp[base + t] = excl; cu[base + t] = excl; }
    __syncthreads();
    if (t == 255) carry = buf[255] + carry;
    __syncthreads();
  }
  if (t == 0) rp[NN] = carry;
}

__global__ __launch_bounds__(256) void scat_k(const int* __restrict__ ei0,
                                              const int* __restrict__ ei1,
                                              int* __restrict__ cursor,
                                              int* __restrict__ srcs) {
  const int e = blockIdx.x * 256 + threadIdx.x;
  if (e >= EE) return;
  const int et = blockIdx.y;
  const int* ei = et ? ei1 : ei0;
  const int s = ei[e], d = ei[EE + e];
  const int pos = atomicAdd(&cursor[et * NN + d], 1);
  srcs[et * EE + pos] = s;
}

// ---------------- embed: h = x @ Win + bin + te + pos
__global__ __launch_bounds__(128) void embed_k(
    const void* __restrict__ x, const float* __restrict__ Win,
    const float* __restrict__ bin, const float* __restrict__ te,
    const void* __restrict__ pos, const int* __restrict__ flag, float* __restrict__ h) {
  __shared__ float Ws[64][128];
  __shared__ float xs[16][64];
  const int f32in = *flag;
  const int j = threadIdx.x;
  const int base = blockIdx.x * 16;
  for (int i = 0; i < 64; ++i) Ws[i][j] = Win[i * 128 + j];
  for (int r = 0; r < 8; ++r) {
    int idx = r * 128 + j;
    int row = idx >> 6, k = idx & 63;
    size_t gi = (size_t)(base + row) * 64 + k;
    xs[row][k] = f32in ? ((const float*)x)[gi] : u2f(((const u16*)x)[gi]);
  }
  __syncthreads();
  float bj = bin[j] + te[j];
  for (int row = 0; row < 16; ++row) {
    size_t gi = (size_t)(base + row) * 128 + j;
    float pv = f32in ? ((const float*)pos)[gi] : u2f(((const u16*)pos)[gi]);
    float acc = bj + pv;
#pragma unroll
    for (int k = 0; k < 64; ++k) acc += xs[row][k] * Ws[k][j];
    h[(size_t)(base + row) * 128 + j] = acc;
  }
}

// ---------------- MFMA GEMM: C[M,N] = A[M,K]_f32 @ WT(bf16 [N][K]); bias per 1024-col segment
template <int ACT, int OUTB, int ADDS>
__global__ __launch_bounds__(256) void mgemm_k(
    const float* __restrict__ A, const u16* __restrict__ WT,
    const float* __restrict__ b0, const float* __restrict__ b1,
    const float* __restrict__ b2, const float* __restrict__ add,
    float* __restrict__ Cf, u16* __restrict__ Cb, int M, int N, int K) {
  __shared__ __align__(16) u16 Asl[128][40];
  __shared__ __align__(16) u16 Bsl[64][40];
  const int t = threadIdx.x;
  const int lane = t & 63, wid = t >> 6;
  const int bm = blockIdx.y * 128, bn = blockIdx.x * 64;
  const int rg = lane >> 4, rr = lane & 15;
  f32x4 acc[2][4];
#pragma unroll
  for (int i = 0; i < 2; ++i)
#pragma unroll
    for (int j = 0; j < 4; ++j) acc[i][j] = (f32x4){0.f, 0.f, 0.f, 0.f};
  const int ar = t >> 1;
  const int ah = (t & 1) << 4;
  const int wr = t >> 2;
  const int wk = (t & 3) << 3;

  for (int k0 = 0; k0 < K; k0 += 32) {
    const int garow = bm + ar;
    float4 v0 = {0,0,0,0}, v1 = {0,0,0,0}, v2 = {0,0,0,0}, v3 = {0,0,0,0};
    if (garow < M) {
      const float* ap = A + (size_t)garow * K + k0 + ah;
      v0 = *reinterpret_cast<const float4*>(ap);
      v1 = *reinterpret_cast<const float4*>(ap + 4);
      v2 = *reinterpret_cast<const float4*>(ap + 8);
      v3 = *reinterpret_cast<const float4*>(ap + 12);
    }
    u32 pk[8];
    pk[0] = (u32)f2b(v0.x) | ((u32)f2b(v0.y) << 16);
    pk[1] = (u32)f2b(v0.z) | ((u32)f2b(v0.w) << 16);
    pk[2] = (u32)f2b(v1.x) | ((u32)f2b(v1.y) << 16);
    pk[3] = (u32)f2b(v1.z) | ((u32)f2b(v1.w) << 16);
    pk[4] = (u32)f2b(v2.x) | ((u32)f2b(v2.y) << 16);
    pk[5] = (u32)f2b(v2.z) | ((u32)f2b(v2.w) << 16);
    pk[6] = (u32)f2b(v3.x) | ((u32)f2b(v3.y) << 16);
    pk[7] = (u32)f2b(v3.z) | ((u32)f2b(v3.w) << 16);
    uint4 lo = {pk[0], pk[1], pk[2], pk[3]}, hi = {pk[4], pk[5], pk[6], pk[7]};
    *reinterpret_cast<uint4*>(&Asl[ar][ah]) = lo;
    *reinterpret_cast<uint4*>(&Asl[ar][ah + 8]) = hi;
    const uint4 bv = *reinterpret_cast<const uint4*>(WT + (size_t)(bn + wr) * K + k0 + wk);
    *reinterpret_cast<uint4*>(&Bsl[wr][wk]) = bv;
    __syncthreads();
    bf16x8 af[2], bfr[4];
#pragma unroll
    for (int mi = 0; mi < 2; ++mi)
      af[mi] = *reinterpret_cast<const bf16x8*>(&Asl[wid * 32 + mi * 16 + rr][rg * 8]);
#pragma unroll
    for (int ni = 0; ni < 4; ++ni)
      bfr[ni] = *reinterpret_cast<const bf16x8*>(&Bsl[ni * 16 + rr][rg * 8]);
#pragma unroll
    for (int mi = 0; mi < 2; ++mi)
#pragma unroll
      for (int ni = 0; ni < 4; ++ni)
        acc[mi][ni] = __builtin_amdgcn_mfma_f32_16x16x32_bf16(af[mi], bfr[ni], acc[mi][ni], 0, 0, 0);
    __syncthreads();
  }
#pragma unroll
  for (int mi = 0; mi < 2; ++mi) {
#pragma unroll
    for (int ni = 0; ni < 4; ++ni) {
      const int col = bn + ni * 16 + rr;
      const int seg = col >> 10;
      const float* bp = (seg == 0) ? b0 : ((seg == 1) ? b1 : b2);
      const float bcol = bp[col & 1023];
#pragma unroll
      for (int r = 0; r < 4; ++r) {
        const int row = bm + wid * 32 + mi * 16 + rg * 4 + r;
        if (row >= M) continue;
        float v = acc[mi][ni][r] + bcol;
        if (ACT == 1) v = gelu_f(v);
        if (ADDS) v += add[(size_t)row * N + col];
        if (OUTB) Cb[(size_t)row * N + col] = f2b(v);
        else      Cf[(size_t)row * N + col] = v;
      }
    }
  }
}

// ---------------- legacy fp32 vector GEMM (Ws + Wout: precision hedge)
template <int ACT, int OUTB, int ADDS>
__global__ __launch_bounds__(256) void gemm_k(
    const float* __restrict__ A, const float* __restrict__ B,
    const float* __restrict__ bias, const float* __restrict__ add,
    float* __restrict__ Cf, u16* __restrict__ Cb, const int* __restrict__ oflag,
    int M, int N, int K) {
  __shared__ __align__(16) float As[16][64];
  __shared__ __align__(16) float Bs[16][64];
  const int t = threadIdx.x;
  const int tx = t & 15, ty = t >> 4;
  const int bm = blockIdx.y * 64, bn = blockIdx.x * 64;
  float c[4][4] = {{0.f}};
  const int am = t >> 2;
  const int ak = (t & 3) << 2;
  const int bk = t >> 4;
  const int bn4 = (t & 15) << 2;
  for (int k0 = 0; k0 < K; k0 += 16) {
    float4 av = make_float4(0.f, 0.f, 0.f, 0.f);
    const int arow = bm + am;
    if (arow < M) av = *reinterpret_cast<const float4*>(A + (size_t)arow * K + k0 + ak);
    As[ak + 0][am] = av.x; As[ak + 1][am] = av.y;
    As[ak + 2][am] = av.z; As[ak + 3][am] = av.w;
    float4 bv = *reinterpret_cast<const float4*>(B + (size_t)(k0 + bk) * N + bn + bn4);
    Bs[bk][bn4 + 0] = bv.x; Bs[bk][bn4 + 1] = bv.y;
    Bs[bk][bn4 + 2] = bv.z; Bs[bk][bn4 + 3] = bv.w;
    __syncthreads();
#pragma unroll
    for (int kk = 0; kk < 16; ++kk) {
      float4 a = *reinterpret_cast<const float4*>(&As[kk][ty << 2]);
      float4 b = *reinterpret_cast<const float4*>(&Bs[kk][tx << 2]);
      c[0][0] += a.x * b.x; c[0][1] += a.x * b.y; c[0][2] += a.x * b.z; c[0][3] += a.x * b.w;
      c[1][0] += a.y * b.x; c[1][1] += a.y * b.y; c[1][2] += a.y * b.z; c[1][3] += a.y * b.w;
      c[2][0] += a.z * b.x; c[2][1] += a.z * b.y; c[2][2] += a.z * b.z; c[2][3] += a.z * b.w;
      c[3][0] += a.w * b.x; c[3][1] += a.w * b.y; c[3][2] += a.w * b.z; c[3][3] += a.w * b.w;
    }
    __syncthreads();
  }
  const int f32out = (OUTB == 2) ? *oflag : 0;
#pragma unroll
  for (int i = 0; i < 4; ++i) {
    const int row = bm + (ty << 2) + i;
    if (row >= M) continue;
#pragma unroll
    for (int j = 0; j < 4; ++j) {
      const int col = bn + (tx << 2) + j;
      float v = c[i][j] + bias[col];
      if (ACT == 1) v = gelu_f(v);
      if (ADDS) v += add[(size_t)row * N + col];
      if (OUTB == 0)      Cf[(size_t)row * N + col] = v;
      else if (OUTB == 1) Cb[(size_t)row * N + col] = f2b(v);
      else {
        if (f32out) Cf[(size_t)row * N + col] = v;
        else        Cb[(size_t)row * N + col] = f2b(v);
      }
    }
  }
}

// ---------------- fused per-dst flash attention over CSR edge lists
// kvqS rows: [k(1024) | v(1024) | ...]; kvqD rows: q at offset 2048. One wave per dst.
__global__ __launch_bounds__(256) void attn_k(
    const u16* __restrict__ kvqS, const u16* __restrict__ kvqD,
    const int* __restrict__ rowptr, const int* __restrict__ srcs,
    float* __restrict__ agg) {
  const int d = (blockIdx.x * 256 + threadIdx.x) >> 6;
  const int lane = threadIdx.x & 63;
  // load q fragment: 16 bf16
  const u16* qp = kvqD + (size_t)d * KVQ + 2048 + lane * 16;
  uint4 q0 = *reinterpret_cast<const uint4*>(qp);
  uint4 q1 = *reinterpret_cast<const uint4*>(qp + 8);
  float qf[16];
  {
    u32 w[8] = {q0.x, q0.y, q0.z, q0.w, q1.x, q1.y, q1.z, q1.w};
#pragma unroll
    for (int i = 0; i < 8; ++i) { qf[2*i] = u2f(w[i] & 0xffffu); qf[2*i+1] = u2f(w[i] >> 16); }
  }
  float m = -INFINITY, den = 0.f;
  float acc[16];
#pragma unroll
  for (int i = 0; i < 16; ++i) acc[i] = 0.f;
  const int beg = rowptr[d], end = rowptr[d + 1];
  for (int idx = beg; idx < end; ++idx) {
    const int s = srcs[idx];
    const u16* kp = kvqS + (size_t)s * KVQ + lane * 16;
    uint4 k0 = *reinterpret_cast<const uint4*>(kp);
    uint4 k1 = *reinterpret_cast<const uint4*>(kp + 8);
    uint4 w0 = *reinterpret_cast<const uint4*>(kp + 1024);
    uint4 w1 = *reinterpret_cast<const uint4*>(kp + 1024 + 8);
    float part = 0.f;
    {
      u32 w[8] = {k0.x, k0.y, k0.z, k0.w, k1.x, k1.y, k1.z, k1.w};
#pragma unroll
      for (int i = 0; i < 8; ++i) {
        part += qf[2*i] * u2f(w[i] & 0xffffu);
        part += qf[2*i+1] * u2f(w[i] >> 16);
      }
    }
    part += __shfl_xor(part, 1);
    part += __shfl_xor(part, 2);
    part += __shfl_xor(part, 4);
    const float lg = part * 0.088388347648318447f;  // 1/sqrt(128)
    const float nm = fmaxf(m, lg);
    const float cor = __expf(m - nm);
    const float p = __expf(lg - nm);
    den = den * cor + p;
    float vf[16];
    {
      u32 w[8] = {w0.x, w0.y, w0.z, w0.w, w1.x, w1.y, w1.z, w1.w};
#pragma unroll
      for (int i = 0; i < 8; ++i) { vf[2*i] = u2f(w[i] & 0xffffu); vf[2*i+1] = u2f(w[i] >> 16); }
    }
#pragma unroll
    for (int i = 0; i < 16; ++i) acc[i] = acc[i] * cor + p * vf[i];
    m = nm;
  }
  const float inv = 0.125f / (den + 1e-16f);  // 1/8 head mean folded in
  float o[16];
#pragma unroll
  for (int i = 0; i < 16; ++i) {
    float tv = acc[i] * inv;
    tv += __shfl_xor(tv, 8);
    tv += __shfl_xor(tv, 16);
    tv += __shfl_xor(tv, 32);
    o[i] = tv;
  }
  if (lane < 8) {
    float* op = agg + (size_t)d * HIDD + lane * 16;
    *reinterpret_cast<float4*>(op + 0)  = make_float4(o[0],  o[1],  o[2],  o[3]);
    *reinterpret_cast<float4*>(op + 4)  = make_float4(o[4],  o[5],  o[6],  o[7]);
    *reinterpret_cast<float4*>(op + 8)  = make_float4(o[8],  o[9],  o[10], o[11]);
    *reinterpret_cast<float4*>(op + 12) = make_float4(o[12], o[13], o[14], o[15]);
  }
}

// ---------------- beta gate + skip (wave per node)
__global__ __launch_bounds__(256) void beta_k(
    const float* __restrict__ agg, const float* __restrict__ xr,
    const float* __restrict__ Wb, float* __restrict__ outn) {
  const int n = (blockIdx.x * blockDim.x + threadIdx.x) >> 6;
  if (n >= NN) return;
  const int lane = threadIdx.x & 63;
  const float o0 = agg[(size_t)n * HIDD + lane], o1 = agg[(size_t)n * HIDD + 64 + lane];
  const float x0 = xr[(size_t)n * HIDD + lane], x1 = xr[(size_t)n * HIDD + 64 + lane];
  float s = o0 * Wb[lane] + o1 * Wb[64 + lane]
          + x0 * Wb[128 + lane] + x1 * Wb[192 + lane]
          + (o0 - x0) * Wb[256 + lane] + (o1 - x1) * Wb[320 + lane];
#pragma unroll
  for (int mask = 1; mask < 64; mask <<= 1) s += __shfl_xor(s, mask);
  const float beta = 1.f / (1.f + expf(-s));
  outn[(size_t)n * HIDD + lane]      = beta * x0 + (1.f - beta) * o0;
  outn[(size_t)n * HIDD + 64 + lane] = beta * x1 + (1.f - beta) * o1;
}

// ---------------- layernorm of (h + new)
__global__ __launch_bounds__(256) void ln_k(
    const float* __restrict__ h, const float* __restrict__ nw,
    const float* __restrict__ g, const float* __restrict__ b, float* __restrict__ r) {
  const int n = (blockIdx.x * blockDim.x + threadIdx.x) >> 6;
  if (n >= NN) return;
  const int lane = threadIdx.x & 63;
  const float v0 = h[(size_t)n * HIDD + lane] + nw[(size_t)n * HIDD + lane];
  const float v1 = h[(size_t)n * HIDD + 64 + lane] + nw[(size_t)n * HIDD + 64 + lane];
  float s = v0 + v1;
#pragma unroll
  for (int mask = 1; mask < 64; mask <<= 1) s += __shfl_xor(s, mask);
  const float mu = s * (1.f / 128.f);
  const float d0 = v0 - mu, d1 = v1 - mu;
  float vs = d0 * d0 + d1 * d1;
#pragma unroll
  for (int mask = 1; mask < 64; mask <<= 1) vs += __shfl_xor(vs, mask);
  const float rstd = rsqrtf(vs * (1.f / 128.f) + 1e-5f);
  r[(size_t)n * HIDD + lane]      = d0 * rstd * g[lane] + b[lane];
  r[(size_t)n * HIDD + 64 + lane] = d1 * rstd * g[64 + lane] + b[64 + lane];
}

extern "C" void kernel_launch(void* const* d_in, const int* in_sizes, int n_in,
                              void* d_out, int out_size, void* d_ws, size_t ws_size,
                              hipStream_t stream) {
  char* w = (char*)d_ws;
  auto carve = [&](size_t bytes) { void* p = (void*)w; w += (bytes + 255) & ~(size_t)255; return p; };
  float* h_b[2];   h_b[0] = (float*)carve((size_t)NN * HIDD * 4); h_b[1] = (float*)carve((size_t)NN * HIDD * 4);
  float* new_b[2]; new_b[0] = (float*)carve((size_t)NN * HIDD * 4); new_b[1] = (float*)carve((size_t)NN * HIDD * 4);
  float* rbuf = (float*)carve((size_t)NN * HIDD * 4);
  float* aggb = (float*)carve((size_t)NN * HIDD * 4);
  float* xrb  = (float*)carve((size_t)NN * HIDD * 4);
  u16* kvqJ = (u16*)carve((size_t)NN * KVQ * 2);   // [K_jm|V_jm|Q_mj] bf16
  u16* kvqM = (u16*)carve((size_t)NN * KVQ * 2);   // [K_mj|V_mj|Q_jm] bf16
  float* mid = (float*)kvqJ;                        // alias: FFN mid used only after attn
  int* histb  = (int*)carve(2 * NN * 4);
  int* rowptr = (int*)carve(2 * (NN + 1) * 4);
  int* cursor = (int*)carve(2 * NN * 4);
  int* srcsb  = (int*)carve(2 * EE * 4);
  int* flagp  = (int*)carve(256);
  const int totCvt = 2 * 26752 + 2 * 39936;  // 133,376 small f32 params
  float* wf = (float*)carve((size_t)totCvt * 4);
  u16* wtp = (u16*)carve((size_t)2097152 * 2);

  // ---- f32 conversion table (small tensors) ----
  CvtArgs ca; int nc = 0; int cum = 0;
  auto addc = [&](int inIdx, int n) -> float* {
    ca.src[nc] = d_in[inIdx]; ca.cnt[nc] = n; float* p = wf + cum; cum += n; ++nc; return p;
  };
  const float *WinF[2], *binF[2], *teF[2], *lngF[2], *lnbF[2], *b1F[2], *b2F[2], *WoutF[2], *boutF[2];
  const void* x_p[2]; const void* pos_p[2];
  for (int t = 0; t < 2; ++t) {
    const int o = t * 13;
    x_p[t] = d_in[o + 0];
    WinF[t] = addc(o + 1, 64 * HIDD);
    binF[t] = addc(o + 2, HIDD);
    pos_p[t] = d_in[o + 3];
    teF[t]  = addc(o + 4, HIDD);
    lngF[t] = addc(o + 5, 2 * HIDD);
    lnbF[t] = addc(o + 6, 2 * HIDD);
    b1F[t]  = addc(o + 8, 2 * FFD);
    b2F[t]  = addc(o + 10, 2 * HIDD);
    WoutF[t] = addc(o + 11, HIDD * HIDD);
    boutF[t] = addc(o + 12, HIDD);
  }
  const float *WsF[2], *WbF[2], *bqF[2], *bkF[2], *bvF[2], *bsF[2];
  const int* ei_e[2];
  for (int et = 0; et < 2; ++et) {
    const int o = 26 + et * 10;
    WsF[et] = addc(o + 3, 2 * HIDD * HIDD);
    WbF[et] = addc(o + 4, 2 * 384);
    bqF[et] = addc(o + 5, 2 * INNERD);
    bkF[et] = addc(o + 6, 2 * INNERD);
    bvF[et] = addc(o + 7, 2 * INNERD);
    bsF[et] = addc(o + 8, 2 * HIDD);
    ei_e[et] = (const int*)d_in[o + 9];
  }
  ca.ntot = cum;

  // ---- transpose table: per (et,l) concat [Wk_et|Wv_et|Wq_OTHER] -> [3072][128]; plus W1,W2
  // kvqJ rows serve: K/V as src of jm (et=0 weights), Q as dst of mj (et=1 weights). And vice versa.
  TTab tt; int ntt = 0; u16* tcur = wtp;
  auto addT = [&](const void* s, long off, int K, int N, u16* dst) {
    tt.m[ntt] = {s, off, dst, K, N}; ++ntt;
  };
  u16* kvqWT[2][2];  // [et][l] -> [3072][128]
  for (int et = 0; et < 2; ++et) {
    const int o  = 26 + et * 10;        // this edge type (K,V weights)
    const int oq = 26 + (1 - et) * 10;  // OTHER edge type (Q weights)  <-- round-5 bugfix
    for (int l = 0; l < 2; ++l) {
      u16* base = tcur; tcur += (size_t)KVQ * HIDD;
      kvqWT[et][l] = base;
      addT(d_in[o + 1],  (long)l * HIDD * INNERD, HIDD, INNERD, base);                 // Wk_et
      addT(d_in[o + 2],  (long)l * HIDD * INNERD, HIDD, INNERD, base + 1024 * HIDD);  // Wv_et
      addT(d_in[oq + 0], (long)l * HIDD * INNERD, HIDD, INNERD, base + 2048 * HIDD);  // Wq_other
    }
  }
  u16 *W1T[2][2], *W2T[2][2];
  for (int t = 0; t < 2; ++t) {
    const int o = t * 13;
    for (int l = 0; l < 2; ++l) {
      W1T[t][l] = tcur; addT(d_in[o + 7], (long)l * HIDD * FFD, HIDD, FFD, tcur); tcur += (size_t)HIDD * FFD;
      W2T[t][l] = tcur; addT(d_in[o + 9], (long)l * FFD * HIDD, FFD, HIDD, tcur); tcur += (size_t)FFD * HIDD;
    }
  }

  const dim3 blk(256);
  const int MB64 = (NN + 63) / 64;
  const int MB128 = (NN + 127) / 128;

  // ---- prep: detect, convert, transpose, CSR ----
  detect_k<<<1, 64, 0, stream>>>((const u32*)d_in[0], flagp);
  convert_k<<<(cum + 255) / 256, blk, 0, stream>>>(ca, flagp, wf);
  transT_k<<<dim3(32, 16, 20), dim3(32, 8), 0, stream>>>(tt, flagp);
  hipMemsetAsync(histb, 0, 2 * NN * 4, stream);
  hist_k<<<dim3((EE + 255) / 256, 2), blk, 0, stream>>>(ei_e[0], ei_e[1], histb);
  scan_k<<<2, blk, 0, stream>>>(histb, rowptr, cursor);
  scat_k<<<dim3((EE + 255) / 256, 2), blk, 0, stream>>>(ei_e[0], ei_e[1], cursor, srcsb);

  // ---- embed ----
  embed_k<<<NN / 16, 128, 0, stream>>>(x_p[0], WinF[0], binF[0], teF[0], pos_p[0], flagp, h_b[0]);
  embed_k<<<NN / 16, 128, 0, stream>>>(x_p[1], WinF[1], binF[1], teF[1], pos_p[1], flagp, h_b[1]);

  for (int l = 0; l < 2; ++l) {
    // batched projections: A=h_j -> kvqJ [K_jm|V_jm|Q_mj]; A=h_m -> kvqM [K_mj|V_mj|Q_jm]
    const dim3 gq(KVQ / 64, MB128);
    mgemm_k<0, 1, 0><<<gq, blk, 0, stream>>>(h_b[0], kvqWT[0][l],
        bkF[0] + l * INNERD, bvF[0] + l * INNERD, bqF[1] + l * INNERD,
        nullptr, nullptr, kvqJ, NN, KVQ, HIDD);
    mgemm_k<0, 1, 0><<<gq, blk, 0, stream>>>(h_b[1], kvqWT[1][l],
        bkF[1] + l * INNERD, bvF[1] + l * INNERD, bqF[0] + l * INNERD,
        nullptr, nullptr, kvqM, NN, KVQ, HIDD);
    // jm: src=job (k/v in kvqJ), dst=mach (q in kvqM)
    attn_k<<<(NN * 64) / 256, blk, 0, stream>>>(kvqJ, kvqM, rowptr, srcsb, aggb);
    gemm_k<0, 0, 0><<<dim3(HIDD / 64, MB64), blk, 0, stream>>>(h_b[1],
        WsF[0] + (size_t)l * HIDD * HIDD, bsF[0] + l * HIDD, nullptr, xrb, nullptr, nullptr,
        NN, HIDD, HIDD);
    beta_k<<<(NN * 64) / 256, blk, 0, stream>>>(aggb, xrb, WbF[0] + l * 384, new_b[1]);
    // mj: src=mach (k/v in kvqM), dst=job (q in kvqJ)
    attn_k<<<(NN * 64) / 256, blk, 0, stream>>>(kvqM, kvqJ, rowptr + (NN + 1), srcsb + EE, aggb);
    gemm_k<0, 0, 0><<<dim3(HIDD / 64, MB64), blk, 0, stream>>>(h_b[0],
        WsF[1] + (size_t)l * HIDD * HIDD, bsF[1] + l * HIDD, nullptr, xrb, nullptr, nullptr,
        NN, HIDD, HIDD);
    beta_k<<<(NN * 64) / 256, blk, 0, stream>>>(aggb, xrb, WbF[1] + l * 384, new_b[0]);
    // FFN (mid aliases kvqJ -- safe: kvq fully rewritten next layer)
    for (int t = 0; t < 2; ++t) {
      ln_k<<<(NN * 64) / 256, blk, 0, stream>>>(h_b[t], new_b[t],
          lngF[t] + l * HIDD, lnbF[t] + l * HIDD, rbuf);
      mgemm_k<1, 0, 0><<<dim3(FFD / 64, MB128), blk, 0, stream>>>(rbuf, W1T[t][l],
          b1F[t] + l * FFD, b1F[t] + l * FFD, b1F[t] + l * FFD, nullptr, mid, nullptr,
          NN, FFD, HIDD);
      mgemm_k<0, 0, 1><<<dim3(HIDD / 64, MB128), blk, 0, stream>>>(mid, W2T[t][l],
          b2F[t] + l * HIDD, b2F[t] + l * HIDD, b2F[t] + l * HIDD, rbuf, h_b[t], nullptr,
          NN, HIDD, FFD);
    }
  }
  const dim3 go(HIDD / 64, MB64);
  gemm_k<0, 2, 0><<<go, blk, 0, stream>>>(h_b[0], WoutF[0], boutF[0], nullptr,
      (float*)d_out, (u16*)d_out, flagp, NN, HIDD, HIDD);
  gemm_k<0, 2, 0><<<go, blk, 0, stream>>>(h_b[1], WoutF[1], boutF[1], nullptr,
      (float*)d_out + (size_t)NN * HIDD, (u16*)d_out + (size_t)NN * HIDD, flagp,
      NN, HIDD, HIDD);
}

// Round 7
// 527.216 us; speedup vs baseline: 2.2686x; 1.2887x over previous
//
#include <hip/hip_runtime.h>
#include <hip/hip_bf16.h>

#define NN 10000
#define EE 60000
#define HIDD 128
#define NH 8
#define INNERD 1024
#define FFD 512
#define KVQ 3072

using u16 = unsigned short;
using u32 = unsigned int;

typedef __bf16 bf16x8 __attribute__((ext_vector_type(8)));
typedef float f32x4 __attribute__((ext_vector_type(4)));

__device__ __forceinline__ float u2f(u32 u) { return __uint_as_float(u << 16); }
__device__ __forceinline__ u16 f2b(float f) {  // RNE
  u32 x = __float_as_uint(f);
  return (u16)((x + 0x7fffu + ((x >> 16) & 1u)) >> 16);
}
__device__ __forceinline__ float gelu_f(float x) {
  return 0.5f * x * (1.0f + erff(x * 0.70710678118654752f));
}

// ---------------- dtype detect (runtime hedge, flag=1 means f32 inputs)
__global__ void detect_k(const u32* __restrict__ xw, int* __restrict__ flag) {
  if (threadIdx.x == 0 && blockIdx.x == 0) {
    int wild = 0;
    for (int i = 0; i < 256; ++i) {
      float v = u2f(xw[i] & 0xffffu);
      if (!(fabsf(v) < 1e4f)) ++wild;
    }
    *flag = (wild > 16) ? 1 : 0;
  }
}

#define NCVT 30
struct CvtArgs { const void* src[NCVT]; int cnt[NCVT]; int ntot; };

__global__ __launch_bounds__(256) void convert_k(CvtArgs a, const int* __restrict__ flag,
                                                 float* __restrict__ dst) {
  const int i = blockIdx.x * 256 + threadIdx.x;
  if (i >= a.ntot) return;
  int t = 0, off = i;
  while (off >= a.cnt[t]) { off -= a.cnt[t]; ++t; }
  const float v = (*flag) ? ((const float*)a.src[t])[off]
                          : u2f(((const u16*)a.src[t])[off]);
  dst[i] = v;
}

// ---------------- batched weight transpose: W[K][N] -> WT bf16 [N][K]
struct TT { const void* s; long off; u16* d; int K; int N; };
struct TTab { TT m[20]; };

__global__ __launch_bounds__(256) void transT_k(TTab tt, const int* __restrict__ flag) {
  const TT m = tt.m[blockIdx.z];
  const int n0 = blockIdx.x * 32, k0 = blockIdx.y * 32;
  if (n0 >= m.N || k0 >= m.K) return;
  __shared__ float tile[32][33];
  const int c = threadIdx.x;
  const int f32in = *flag;
  for (int i = threadIdx.y; i < 32; i += 8) {
    const long gi = m.off + (long)(k0 + i) * m.N + n0 + c;
    tile[i][c] = f32in ? ((const float*)m.s)[gi] : u2f(((const u16*)m.s)[gi]);
  }
  __syncthreads();
  for (int i = threadIdx.y; i < 32; i += 8)
    m.d[(size_t)(n0 + i) * m.K + k0 + c] = f2b(tile[c][i]);
}

// ---------------- CSR build
__global__ __launch_bounds__(256) void hist_k(const int* __restrict__ ei0,
                                              const int* __restrict__ ei1,
                                              int* __restrict__ hist) {
  const int e = blockIdx.x * 256 + threadIdx.x;
  if (e >= EE) return;
  const int et = blockIdx.y;
  const int* ei = et ? ei1 : ei0;
  atomicAdd(&hist[et * NN + ei[EE + e]], 1);
}

// fast wave-shuffle scan: 1 block of 1024 per edge type
__global__ __launch_bounds__(1024) void scan2_k(const int* __restrict__ hist,
                                                int* __restrict__ rowptr,
                                                int* __restrict__ cursor) {
  const int et = blockIdx.x;
  const int* h = hist + et * NN;
  int* rp = rowptr + et * (NN + 1);
  int* cu = cursor + et * NN;
  __shared__ int wsum[16];
  __shared__ int carrySm;
  const int t = threadIdx.x, lane = t & 63, wid = t >> 6;
  if (t == 0) carrySm = 0;
  __syncthreads();
  for (int base = 0; base < NN; base += 1024) {
    const int idx = base + t;
    const int v = (idx < NN) ? h[idx] : 0;
    int x = v;
#pragma unroll
    for (int off = 1; off < 64; off <<= 1) {
      int y = __shfl_up(x, off);
      if (lane >= off) x += y;
    }
    if (lane == 63) wsum[wid] = x;
    __syncthreads();
    if (wid == 0) {
      int s = (lane < 16) ? wsum[lane] : 0;
#pragma unroll
      for (int off = 1; off < 16; off <<= 1) {
        int y = __shfl_up(s, off);
        if (lane >= off) s += y;
      }
      if (lane < 16) wsum[lane] = s;
    }
    __syncthreads();
    const int waveoff = (wid > 0) ? wsum[wid - 1] : 0;
    const int incl = x + waveoff + carrySm;
    if (idx < NN) { rp[idx] = incl - v; cu[idx] = incl - v; }
    __syncthreads();
    if (t == 1023) carrySm = incl;
    __syncthreads();
  }
  if (t == 0) rp[NN] = carrySm;
}

__global__ __launch_bounds__(256) void scat_k(const int* __restrict__ ei0,
                                              const int* __restrict__ ei1,
                                              int* __restrict__ cursor,
                                              int* __restrict__ srcs) {
  const int e = blockIdx.x * 256 + threadIdx.x;
  if (e >= EE) return;
  const int et = blockIdx.y;
  const int* ei = et ? ei1 : ei0;
  const int s = ei[e], d = ei[EE + e];
  const int pos = atomicAdd(&cursor[et * NN + d], 1);
  srcs[et * EE + pos] = s;
}

// ---------------- embed both types: h = x @ Win + bin + te + pos (y = type)
__global__ __launch_bounds__(128) void embed2_k(
    const void* __restrict__ x0, const float* __restrict__ Win0,
    const float* __restrict__ bin0, const float* __restrict__ te0,
    const void* __restrict__ pos0, float* __restrict__ h0,
    const void* __restrict__ x1, const float* __restrict__ Win1,
    const float* __restrict__ bin1, const float* __restrict__ te1,
    const void* __restrict__ pos1, float* __restrict__ h1,
    const int* __restrict__ flag) {
  const int ty = blockIdx.y;
  const void* x = ty ? x1 : x0;
  const float* Win = ty ? Win1 : Win0;
  const float* bin = ty ? bin1 : bin0;
  const float* te = ty ? te1 : te0;
  const void* pos = ty ? pos1 : pos0;
  float* h = ty ? h1 : h0;
  __shared__ float Ws[64][128];
  __shared__ float xs[16][64];
  const int f32in = *flag;
  const int j = threadIdx.x;
  const int base = blockIdx.x * 16;
  for (int i = 0; i < 64; ++i) Ws[i][j] = Win[i * 128 + j];
  for (int r = 0; r < 8; ++r) {
    int idx = r * 128 + j;
    int row = idx >> 6, k = idx & 63;
    size_t gi = (size_t)(base + row) * 64 + k;
    xs[row][k] = f32in ? ((const float*)x)[gi] : u2f(((const u16*)x)[gi]);
  }
  __syncthreads();
  float bj = bin[j] + te[j];
  for (int row = 0; row < 16; ++row) {
    size_t gi = (size_t)(base + row) * 128 + j;
    float pv = f32in ? ((const float*)pos)[gi] : u2f(((const u16*)pos)[gi]);
    float acc = bj + pv;
#pragma unroll
    for (int k = 0; k < 64; ++k) acc += xs[row][k] * Ws[k][j];
    h[(size_t)(base + row) * 128 + j] = acc;
  }
}

// ---------------- MFMA GEMM, dual-task via blockIdx.z
struct MG {
  const float* A; const u16* WT;
  const float* b0; const float* b1; const float* b2;
  const float* add; float* Cf; u16* Cb;
};

template <int ACT, int OUTB, int ADDS>
__global__ __launch_bounds__(256) void mgemm2_k(MG g0, MG g1, int M, int N, int K) {
  const MG g = blockIdx.z ? g1 : g0;
  __shared__ __align__(16) u16 Asl[128][40];
  __shared__ __align__(16) u16 Bsl[64][40];
  const int t = threadIdx.x;
  const int lane = t & 63, wid = t >> 6;
  const int bm = blockIdx.y * 128, bn = blockIdx.x * 64;
  const int rg = lane >> 4, rr = lane & 15;
  f32x4 acc[2][4];
#pragma unroll
  for (int i = 0; i < 2; ++i)
#pragma unroll
    for (int j = 0; j < 4; ++j) acc[i][j] = (f32x4){0.f, 0.f, 0.f, 0.f};
  const int ar = t >> 1;
  const int ah = (t & 1) << 4;
  const int wr = t >> 2;
  const int wk = (t & 3) << 3;

  for (int k0 = 0; k0 < K; k0 += 32) {
    const int garow = bm + ar;
    float4 v0 = {0,0,0,0}, v1 = {0,0,0,0}, v2 = {0,0,0,0}, v3 = {0,0,0,0};
    if (garow < M) {
      const float* ap = g.A + (size_t)garow * K + k0 + ah;
      v0 = *reinterpret_cast<const float4*>(ap);
      v1 = *reinterpret_cast<const float4*>(ap + 4);
      v2 = *reinterpret_cast<const float4*>(ap + 8);
      v3 = *reinterpret_cast<const float4*>(ap + 12);
    }
    u32 pk[8];
    pk[0] = (u32)f2b(v0.x) | ((u32)f2b(v0.y) << 16);
    pk[1] = (u32)f2b(v0.z) | ((u32)f2b(v0.w) << 16);
    pk[2] = (u32)f2b(v1.x) | ((u32)f2b(v1.y) << 16);
    pk[3] = (u32)f2b(v1.z) | ((u32)f2b(v1.w) << 16);
    pk[4] = (u32)f2b(v2.x) | ((u32)f2b(v2.y) << 16);
    pk[5] = (u32)f2b(v2.z) | ((u32)f2b(v2.w) << 16);
    pk[6] = (u32)f2b(v3.x) | ((u32)f2b(v3.y) << 16);
    pk[7] = (u32)f2b(v3.z) | ((u32)f2b(v3.w) << 16);
    uint4 lo = {pk[0], pk[1], pk[2], pk[3]}, hi = {pk[4], pk[5], pk[6], pk[7]};
    *reinterpret_cast<uint4*>(&Asl[ar][ah]) = lo;
    *reinterpret_cast<uint4*>(&Asl[ar][ah + 8]) = hi;
    const uint4 bv = *reinterpret_cast<const uint4*>(g.WT + (size_t)(bn + wr) * K + k0 + wk);
    *reinterpret_cast<uint4*>(&Bsl[wr][wk]) = bv;
    __syncthreads();
    bf16x8 af[2], bfr[4];
#pragma unroll
    for (int mi = 0; mi < 2; ++mi)
      af[mi] = *reinterpret_cast<const bf16x8*>(&Asl[wid * 32 + mi * 16 + rr][rg * 8]);
#pragma unroll
    for (int ni = 0; ni < 4; ++ni)
      bfr[ni] = *reinterpret_cast<const bf16x8*>(&Bsl[ni * 16 + rr][rg * 8]);
#pragma unroll
    for (int mi = 0; mi < 2; ++mi)
#pragma unroll
      for (int ni = 0; ni < 4; ++ni)
        acc[mi][ni] = __builtin_amdgcn_mfma_f32_16x16x32_bf16(af[mi], bfr[ni], acc[mi][ni], 0, 0, 0);
    __syncthreads();
  }
#pragma unroll
  for (int mi = 0; mi < 2; ++mi) {
#pragma unroll
    for (int ni = 0; ni < 4; ++ni) {
      const int col = bn + ni * 16 + rr;
      const int seg = col >> 10;
      const float* bp = (seg == 0) ? g.b0 : ((seg == 1) ? g.b1 : g.b2);
      const float bcol = bp[col & 1023];
#pragma unroll
      for (int r = 0; r < 4; ++r) {
        const int row = bm + wid * 32 + mi * 16 + rg * 4 + r;
        if (row >= M) continue;
        float v = acc[mi][ni][r] + bcol;
        if (ACT == 1) v = gelu_f(v);
        if (ADDS) v += g.add[(size_t)row * N + col];
        if (OUTB) g.Cb[(size_t)row * N + col] = f2b(v);
        else      g.Cf[(size_t)row * N + col] = v;
      }
    }
  }
}

// ---------------- legacy fp32 vector GEMM, dual-task via blockIdx.z (Ws + Wout hedge)
struct VG {
  const float* A; const float* B; const float* bias;
  const float* add; float* Cf; u16* Cb;
};

template <int ACT, int OUTB, int ADDS>
__global__ __launch_bounds__(256) void gemm2_k(VG g0, VG g1, const int* __restrict__ oflag,
                                               int M, int N, int K) {
  const VG g = blockIdx.z ? g1 : g0;
  __shared__ __align__(16) float As[16][64];
  __shared__ __align__(16) float Bs[16][64];
  const int t = threadIdx.x;
  const int tx = t & 15, ty = t >> 4;
  const int bm = blockIdx.y * 64, bn = blockIdx.x * 64;
  float c[4][4] = {{0.f}};
  const int am = t >> 2;
  const int ak = (t & 3) << 2;
  const int bk = t >> 4;
  const int bn4 = (t & 15) << 2;
  for (int k0 = 0; k0 < K; k0 += 16) {
    float4 av = make_float4(0.f, 0.f, 0.f, 0.f);
    const int arow = bm + am;
    if (arow < M) av = *reinterpret_cast<const float4*>(g.A + (size_t)arow * K + k0 + ak);
    As[ak + 0][am] = av.x; As[ak + 1][am] = av.y;
    As[ak + 2][am] = av.z; As[ak + 3][am] = av.w;
    float4 bv = *reinterpret_cast<const float4*>(g.B + (size_t)(k0 + bk) * N + bn + bn4);
    Bs[bk][bn4 + 0] = bv.x; Bs[bk][bn4 + 1] = bv.y;
    Bs[bk][bn4 + 2] = bv.z; Bs[bk][bn4 + 3] = bv.w;
    __syncthreads();
#pragma unroll
    for (int kk = 0; kk < 16; ++kk) {
      float4 a = *reinterpret_cast<const float4*>(&As[kk][ty << 2]);
      float4 b = *reinterpret_cast<const float4*>(&Bs[kk][tx << 2]);
      c[0][0] += a.x * b.x; c[0][1] += a.x * b.y; c[0][2] += a.x * b.z; c[0][3] += a.x * b.w;
      c[1][0] += a.y * b.x; c[1][1] += a.y * b.y; c[1][2] += a.y * b.z; c[1][3] += a.y * b.w;
      c[2][0] += a.z * b.x; c[2][1] += a.z * b.y; c[2][2] += a.z * b.z; c[2][3] += a.z * b.w;
      c[3][0] += a.w * b.x; c[3][1] += a.w * b.y; c[3][2] += a.w * b.z; c[3][3] += a.w * b.w;
    }
    __syncthreads();
  }
  const int f32out = (OUTB == 2) ? *oflag : 0;
#pragma unroll
  for (int i = 0; i < 4; ++i) {
    const int row = bm + (ty << 2) + i;
    if (row >= M) continue;
#pragma unroll
    for (int j = 0; j < 4; ++j) {
      const int col = bn + (tx << 2) + j;
      float v = c[i][j] + g.bias[col];
      if (ACT == 1) v = gelu_f(v);
      if (ADDS) v += g.add[(size_t)row * N + col];
      if (OUTB == 0)      g.Cf[(size_t)row * N + col] = v;
      else if (OUTB == 1) g.Cb[(size_t)row * N + col] = f2b(v);
      else {
        if (f32out) g.Cf[(size_t)row * N + col] = v;
        else        g.Cb[(size_t)row * N + col] = f2b(v);
      }
    }
  }
}

// ---------------- fused flash attention, both edge types in one dispatch (y = et)
__global__ __launch_bounds__(256) void attn2_k(
    const u16* __restrict__ kvqJ, const u16* __restrict__ kvqM,
    const int* __restrict__ rowptr, const int* __restrict__ srcs,
    float* __restrict__ aggM, float* __restrict__ aggJ) {
  const int et = blockIdx.y;
  const u16* kvqS = et ? kvqM : kvqJ;
  const u16* kvqD = et ? kvqJ : kvqM;
  const int* rp = rowptr + et * (NN + 1);
  const int* sr = srcs + et * EE;
  float* agg = et ? aggJ : aggM;
  const int d = (blockIdx.x * 256 + threadIdx.x) >> 6;
  const int lane = threadIdx.x & 63;
  const u16* qp = kvqD + (size_t)d * KVQ + 2048 + lane * 16;
  uint4 q0 = *reinterpret_cast<const uint4*>(qp);
  uint4 q1 = *reinterpret_cast<const uint4*>(qp + 8);
  float qf[16];
  {
    u32 w[8] = {q0.x, q0.y, q0.z, q0.w, q1.x, q1.y, q1.z, q1.w};
#pragma unroll
    for (int i = 0; i < 8; ++i) { qf[2*i] = u2f(w[i] & 0xffffu); qf[2*i+1] = u2f(w[i] >> 16); }
  }
  float m = -INFINITY, den = 0.f;
  float acc[16];
#pragma unroll
  for (int i = 0; i < 16; ++i) acc[i] = 0.f;
  const int beg = rp[d], end = rp[d + 1];
  for (int idx = beg; idx < end; ++idx) {
    const int s = sr[idx];
    const u16* kp = kvqS + (size_t)s * KVQ + lane * 16;
    uint4 k0 = *reinterpret_cast<const uint4*>(kp);
    uint4 k1 = *reinterpret_cast<const uint4*>(kp + 8);
    uint4 w0 = *reinterpret_cast<const uint4*>(kp + 1024);
    uint4 w1 = *reinterpret_cast<const uint4*>(kp + 1024 + 8);
    float part = 0.f;
    {
      u32 w[8] = {k0.x, k0.y, k0.z, k0.w, k1.x, k1.y, k1.z, k1.w};
#pragma unroll
      for (int i = 0; i < 8; ++i) {
        part += qf[2*i] * u2f(w[i] & 0xffffu);
        part += qf[2*i+1] * u2f(w[i] >> 16);
      }
    }
    part += __shfl_xor(part, 1);
    part += __shfl_xor(part, 2);
    part += __shfl_xor(part, 4);
    const float lg = part * 0.088388347648318447f;  // 1/sqrt(128)
    const float nm = fmaxf(m, lg);
    const float cor = __expf(m - nm);
    const float p = __expf(lg - nm);
    den = den * cor + p;
    float vf[16];
    {
      u32 w[8] = {w0.x, w0.y, w0.z, w0.w, w1.x, w1.y, w1.z, w1.w};
#pragma unroll
      for (int i = 0; i < 8; ++i) { vf[2*i] = u2f(w[i] & 0xffffu); vf[2*i+1] = u2f(w[i] >> 16); }
    }
#pragma unroll
    for (int i = 0; i < 16; ++i) acc[i] = acc[i] * cor + p * vf[i];
    m = nm;
  }
  const float inv = 0.125f / (den + 1e-16f);
  float o[16];
#pragma unroll
  for (int i = 0; i < 16; ++i) {
    float tv = acc[i] * inv;
    tv += __shfl_xor(tv, 8);
    tv += __shfl_xor(tv, 16);
    tv += __shfl_xor(tv, 32);
    o[i] = tv;
  }
  if (lane < 8) {
    float* op = agg + (size_t)d * HIDD + lane * 16;
    *reinterpret_cast<float4*>(op + 0)  = make_float4(o[0],  o[1],  o[2],  o[3]);
    *reinterpret_cast<float4*>(op + 4)  = make_float4(o[4],  o[5],  o[6],  o[7]);
    *reinterpret_cast<float4*>(op + 8)  = make_float4(o[8],  o[9],  o[10], o[11]);
    *reinterpret_cast<float4*>(op + 12) = make_float4(o[12], o[13], o[14], o[15]);
  }
}

// ---------------- fused beta gate + LayerNorm(h + new), both node types (y selects)
struct BL {
  const float* agg; const float* xr; const float* Wb;
  const float* h; const float* g; const float* b; float* r;
};

__global__ __launch_bounds__(256) void betaln2_k(BL p0, BL p1) {
  const BL p = blockIdx.y ? p1 : p0;
  const int n = (blockIdx.x * 256 + threadIdx.x) >> 6;
  const int lane = threadIdx.x & 63;
  const float o0 = p.agg[(size_t)n * HIDD + lane], o1 = p.agg[(size_t)n * HIDD + 64 + lane];
  const float x0 = p.xr[(size_t)n * HIDD + lane], x1 = p.xr[(size_t)n * HIDD + 64 + lane];
  float s = o0 * p.Wb[lane] + o1 * p.Wb[64 + lane]
          + x0 * p.Wb[128 + lane] + x1 * p.Wb[192 + lane]
          + (o0 - x0) * p.Wb[256 + lane] + (o1 - x1) * p.Wb[320 + lane];
#pragma unroll
  for (int mask = 1; mask < 64; mask <<= 1) s += __shfl_xor(s, mask);
  const float beta = 1.f / (1.f + expf(-s));
  const float n0 = beta * x0 + (1.f - beta) * o0;
  const float n1 = beta * x1 + (1.f - beta) * o1;
  // LN(h + new)
  const float v0 = p.h[(size_t)n * HIDD + lane] + n0;
  const float v1 = p.h[(size_t)n * HIDD + 64 + lane] + n1;
  float sm = v0 + v1;
#pragma unroll
  for (int mask = 1; mask < 64; mask <<= 1) sm += __shfl_xor(sm, mask);
  const float mu = sm * (1.f / 128.f);
  const float d0 = v0 - mu, d1 = v1 - mu;
  float vs = d0 * d0 + d1 * d1;
#pragma unroll
  for (int mask = 1; mask < 64; mask <<= 1) vs += __shfl_xor(vs, mask);
  const float rstd = rsqrtf(vs * (1.f / 128.f) + 1e-5f);
  p.r[(size_t)n * HIDD + lane]      = d0 * rstd * p.g[lane] + p.b[lane];
  p.r[(size_t)n * HIDD + 64 + lane] = d1 * rstd * p.g[64 + lane] + p.b[64 + lane];
}

extern "C" void kernel_launch(void* const* d_in, const int* in_sizes, int n_in,
                              void* d_out, int out_size, void* d_ws, size_t ws_size,
                              hipStream_t stream) {
  char* w = (char*)d_ws;
  auto carve = [&](size_t bytes) { void* p = (void*)w; w += (bytes + 255) & ~(size_t)255; return p; };
  float* h_b[2];  h_b[0] = (float*)carve((size_t)NN * HIDD * 4); h_b[1] = (float*)carve((size_t)NN * HIDD * 4);
  float* rb_b[2]; rb_b[0] = (float*)carve((size_t)NN * HIDD * 4); rb_b[1] = (float*)carve((size_t)NN * HIDD * 4);
  float* xr_b[2]; xr_b[0] = (float*)carve((size_t)NN * HIDD * 4); xr_b[1] = (float*)carve((size_t)NN * HIDD * 4);
  float* ag_b[2]; ag_b[0] = (float*)carve((size_t)NN * HIDD * 4); ag_b[1] = (float*)carve((size_t)NN * HIDD * 4);
  u16* kvqJ = (u16*)carve((size_t)NN * KVQ * 2);   // [K_jm|V_jm|Q_mj] bf16
  u16* kvqM = (u16*)carve((size_t)NN * KVQ * 2);   // [K_mj|V_mj|Q_jm] bf16
  float* mid_b[2] = {(float*)kvqJ, (float*)kvqM};   // alias: FFN mid after attn done
  int* histb  = (int*)carve(2 * NN * 4);
  int* rowptr = (int*)carve(2 * (NN + 1) * 4);
  int* cursor = (int*)carve(2 * NN * 4);
  int* srcsb  = (int*)carve(2 * EE * 4);
  int* flagp  = (int*)carve(256);
  const int totCvt = 2 * 26752 + 2 * 39936;
  float* wf = (float*)carve((size_t)totCvt * 4);
  u16* wtp = (u16*)carve((size_t)2097152 * 2);

  // ---- f32 conversion table (small tensors) ----
  CvtArgs ca; int nc = 0; int cum = 0;
  auto addc = [&](int inIdx, int n) -> float* {
    ca.src[nc] = d_in[inIdx]; ca.cnt[nc] = n; float* p = wf + cum; cum += n; ++nc; return p;
  };
  const float *WinF[2], *binF[2], *teF[2], *lngF[2], *lnbF[2], *b1F[2], *b2F[2], *WoutF[2], *boutF[2];
  const void* x_p[2]; const void* pos_p[2];
  for (int t = 0; t < 2; ++t) {
    const int o = t * 13;
    x_p[t] = d_in[o + 0];
    WinF[t] = addc(o + 1, 64 * HIDD);
    binF[t] = addc(o + 2, HIDD);
    pos_p[t] = d_in[o + 3];
    teF[t]  = addc(o + 4, HIDD);
    lngF[t] = addc(o + 5, 2 * HIDD);
    lnbF[t] = addc(o + 6, 2 * HIDD);
    b1F[t]  = addc(o + 8, 2 * FFD);
    b2F[t]  = addc(o + 10, 2 * HIDD);
    WoutF[t] = addc(o + 11, HIDD * HIDD);
    boutF[t] = addc(o + 12, HIDD);
  }
  const float *WsF[2], *WbF[2], *bqF[2], *bkF[2], *bvF[2], *bsF[2];
  const int* ei_e[2];
  for (int et = 0; et < 2; ++et) {
    const int o = 26 + et * 10;
    WsF[et] = addc(o + 3, 2 * HIDD * HIDD);
    WbF[et] = addc(o + 4, 2 * 384);
    bqF[et] = addc(o + 5, 2 * INNERD);
    bkF[et] = addc(o + 6, 2 * INNERD);
    bvF[et] = addc(o + 7, 2 * INNERD);
    bsF[et] = addc(o + 8, 2 * HIDD);
    ei_e[et] = (const int*)d_in[o + 9];
  }
  ca.ntot = cum;

  // ---- transpose table: per (et,l) concat [Wk_et|Wv_et|Wq_OTHER]; plus W1,W2 ----
  TTab tt; int ntt = 0; u16* tcur = wtp;
  auto addT = [&](const void* s, long off, int K, int N, u16* dst) {
    tt.m[ntt] = {s, off, dst, K, N}; ++ntt;
  };
  u16* kvqWT[2][2];
  for (int et = 0; et < 2; ++et) {
    const int o  = 26 + et * 10;
    const int oq = 26 + (1 - et) * 10;  // Q weights from the OTHER edge type
    for (int l = 0; l < 2; ++l) {
      u16* base = tcur; tcur += (size_t)KVQ * HIDD;
      kvqWT[et][l] = base;
      addT(d_in[o + 1],  (long)l * HIDD * INNERD, HIDD, INNERD, base);
      addT(d_in[o + 2],  (long)l * HIDD * INNERD, HIDD, INNERD, base + 1024 * HIDD);
      addT(d_in[oq + 0], (long)l * HIDD * INNERD, HIDD, INNERD, base + 2048 * HIDD);
    }
  }
  u16 *W1T[2][2], *W2T[2][2];
  for (int t = 0; t < 2; ++t) {
    const int o = t * 13;
    for (int l = 0; l < 2; ++l) {
      W1T[t][l] = tcur; addT(d_in[o + 7], (long)l * HIDD * FFD, HIDD, FFD, tcur); tcur += (size_t)HIDD * FFD;
      W2T[t][l] = tcur; addT(d_in[o + 9], (long)l * FFD * HIDD, FFD, HIDD, tcur); tcur += (size_t)FFD * HIDD;
    }
  }

  const dim3 blk(256);
  const int MB64 = (NN + 63) / 64;    // 157
  const int MB128 = (NN + 127) / 128; // 79

  // ---- prep ----
  detect_k<<<1, 64, 0, stream>>>((const u32*)d_in[0], flagp);
  convert_k<<<(cum + 255) / 256, blk, 0, stream>>>(ca, flagp, wf);
  transT_k<<<dim3(32, 16, 20), dim3(32, 8), 0, stream>>>(tt, flagp);
  hipMemsetAsync(histb, 0, 2 * NN * 4, stream);
  hist_k<<<dim3((EE + 255) / 256, 2), blk, 0, stream>>>(ei_e[0], ei_e[1], histb);
  scan2_k<<<2, 1024, 0, stream>>>(histb, rowptr, cursor);
  scat_k<<<dim3((EE + 255) / 256, 2), blk, 0, stream>>>(ei_e[0], ei_e[1], cursor, srcsb);

  // ---- embed (both types) ----
  embed2_k<<<dim3(NN / 16, 2), 128, 0, stream>>>(
      x_p[0], WinF[0], binF[0], teF[0], pos_p[0], h_b[0],
      x_p[1], WinF[1], binF[1], teF[1], pos_p[1], h_b[1], flagp);

  for (int l = 0; l < 2; ++l) {
    // kvq projections, both types
    MG gj = {h_b[0], kvqWT[0][l], bkF[0] + l * INNERD, bvF[0] + l * INNERD,
             bqF[1] + l * INNERD, nullptr, nullptr, kvqJ};
    MG gm = {h_b[1], kvqWT[1][l], bkF[1] + l * INNERD, bvF[1] + l * INNERD,
             bqF[0] + l * INNERD, nullptr, nullptr, kvqM};
    mgemm2_k<0, 1, 0><<<dim3(KVQ / 64, MB128, 2), blk, 0, stream>>>(gj, gm, NN, KVQ, HIDD);
    // attention, both edge types
    attn2_k<<<dim3(NN / 4, 2), blk, 0, stream>>>(kvqJ, kvqM, rowptr, srcsb, ag_b[1], ag_b[0]);
    // root projections (fp32 hedge), both: jm->xr_m (A=h_m), mj->xr_j (A=h_j)
    VG vs0 = {h_b[1], WsF[0] + (size_t)l * HIDD * HIDD, bsF[0] + l * HIDD, nullptr, xr_b[1], nullptr};
    VG vs1 = {h_b[0], WsF[1] + (size_t)l * HIDD * HIDD, bsF[1] + l * HIDD, nullptr, xr_b[0], nullptr};
    gemm2_k<0, 0, 0><<<dim3(HIDD / 64, MB64, 2), blk, 0, stream>>>(vs0, vs1, nullptr, NN, HIDD, HIDD);
    // beta gate + LN, both node types (y=0: mach from jm, y=1: job from mj)
    BL p0 = {ag_b[1], xr_b[1], WbF[0] + l * 384, h_b[1], lngF[1] + l * HIDD, lnbF[1] + l * HIDD, rb_b[1]};
    BL p1 = {ag_b[0], xr_b[0], WbF[1] + l * 384, h_b[0], lngF[0] + l * HIDD, lnbF[0] + l * HIDD, rb_b[0]};
    betaln2_k<<<dim3(NN / 4, 2), blk, 0, stream>>>(p0, p1);
    // FFN W1 (gelu), both types
    MG w1j = {rb_b[0], W1T[0][l], b1F[0] + l * FFD, b1F[0] + l * FFD, b1F[0] + l * FFD,
              nullptr, mid_b[0], nullptr};
    MG w1m = {rb_b[1], W1T[1][l], b1F[1] + l * FFD, b1F[1] + l * FFD, b1F[1] + l * FFD,
              nullptr, mid_b[1], nullptr};
    mgemm2_k<1, 0, 0><<<dim3(FFD / 64, MB128, 2), blk, 0, stream>>>(w1j, w1m, NN, FFD, HIDD);
    // FFN W2 (+residual r), both types
    MG w2j = {mid_b[0], W2T[0][l], b2F[0] + l * HIDD, b2F[0] + l * HIDD, b2F[0] + l * HIDD,
              rb_b[0], h_b[0], nullptr};
    MG w2m = {mid_b[1], W2T[1][l], b2F[1] + l * HIDD, b2F[1] + l * HIDD, b2F[1] + l * HIDD,
              rb_b[1], h_b[1], nullptr};
    mgemm2_k<0, 0, 1><<<dim3(HIDD / 64, MB128, 2), blk, 0, stream>>>(w2j, w2m, NN, HIDD, FFD);
  }
  // output projections (fp32 hedge, runtime dtype), both types
  VG o0 = {h_b[0], WoutF[0], boutF[0], nullptr, (float*)d_out, (u16*)d_out};
  VG o1 = {h_b[1], WoutF[1], boutF[1], nullptr,
           (float*)d_out + (size_t)NN * HIDD, (u16*)d_out + (size_t)NN * HIDD};
  gemm2_k<0, 2, 0><<<dim3(HIDD / 64, MB64, 2), blk, 0, stream>>>(o0, o1, flagp, NN, HIDD, HIDD);
}

// Round 9
// 467.236 us; speedup vs baseline: 2.5599x; 1.1284x over previous
//
#include <hip/hip_runtime.h>
#include <hip/hip_bf16.h>

#define NN 10000
#define EE 60000
#define HIDD 128
#define NH 8
#define INNERD 1024
#define FFD 512
#define KVQ 3072
#define KVQS 3200

using u16 = unsigned short;
using u32 = unsigned int;

typedef __bf16 bf16x8 __attribute__((ext_vector_type(8)));
typedef float f32x4 __attribute__((ext_vector_type(4)));

__device__ __forceinline__ float u2f(u32 u) { return __uint_as_float(u << 16); }
__device__ __forceinline__ u16 f2b(float f) {  // RNE
  u32 x = __float_as_uint(f);
  return (u16)((x + 0x7fffu + ((x >> 16) & 1u)) >> 16);
}
__device__ __forceinline__ float gelu_f(float x) {
  return 0.5f * x * (1.0f + erff(x * 0.70710678118654752f));
}

// ---------------- dtype detect (runtime hedge, flag=1 means f32 inputs)
__global__ void detect_k(const u32* __restrict__ xw, int* __restrict__ flag) {
  if (threadIdx.x == 0 && blockIdx.x == 0) {
    int wild = 0;
    for (int i = 0; i < 256; ++i) {
      float v = u2f(xw[i] & 0xffffu);
      if (!(fabsf(v) < 1e4f)) ++wild;
    }
    *flag = (wild > 16) ? 1 : 0;
  }
}

#define NCVT 30
struct CvtArgs { const void* src[NCVT]; int cnt[NCVT]; int ntot; };

__global__ __launch_bounds__(256) void convert_k(CvtArgs a, const int* __restrict__ flag,
                                                 float* __restrict__ dst) {
  const int i = blockIdx.x * 256 + threadIdx.x;
  if (i >= a.ntot) return;
  int t = 0, off = i;
  while (off >= a.cnt[t]) { off -= a.cnt[t]; ++t; }
  const float v = (*flag) ? ((const float*)a.src[t])[off]
                          : u2f(((const u16*)a.src[t])[off]);
  dst[i] = v;
}

// ---------------- batched weight transpose: W[K][N] -> WT bf16 [N][K]
struct TT { const void* s; long off; u16* d; int K; int N; };
struct TTab { TT m[28]; };

__global__ __launch_bounds__(256) void transT_k(TTab tt, const int* __restrict__ flag) {
  const TT m = tt.m[blockIdx.z];
  const int n0 = blockIdx.x * 32, k0 = blockIdx.y * 32;
  if (n0 >= m.N || k0 >= m.K) return;
  __shared__ float tile[32][33];
  const int c = threadIdx.x;
  const int f32in = *flag;
  for (int i = threadIdx.y; i < 32; i += 8) {
    const long gi = m.off + (long)(k0 + i) * m.N + n0 + c;
    tile[i][c] = f32in ? ((const float*)m.s)[gi] : u2f(((const u16*)m.s)[gi]);
  }
  __syncthreads();
  for (int i = threadIdx.y; i < 32; i += 8)
    m.d[(size_t)(n0 + i) * m.K + k0 + c] = f2b(tile[c][i]);
}

// ---------------- CSR build
__global__ __launch_bounds__(256) void hist_k(const int* __restrict__ ei0,
                                              const int* __restrict__ ei1,
                                              int* __restrict__ hist) {
  const int e = blockIdx.x * 256 + threadIdx.x;
  if (e >= EE) return;
  const int et = blockIdx.y;
  const int* ei = et ? ei1 : ei0;
  atomicAdd(&hist[et * NN + ei[EE + e]], 1);
}

__global__ __launch_bounds__(1024) void scan2_k(const int* __restrict__ hist,
                                                int* __restrict__ rowptr,
                                                int* __restrict__ cursor) {
  const int et = blockIdx.x;
  const int* h = hist + et * NN;
  int* rp = rowptr + et * (NN + 1);
  int* cu = cursor + et * NN;
  __shared__ int wsum[16];
  __shared__ int carrySm;
  const int t = threadIdx.x, lane = t & 63, wid = t >> 6;
  if (t == 0) carrySm = 0;
  __syncthreads();
  for (int base = 0; base < NN; base += 1024) {
    const int idx = base + t;
    const int v = (idx < NN) ? h[idx] : 0;
    int x = v;
#pragma unroll
    for (int off = 1; off < 64; off <<= 1) {
      int y = __shfl_up(x, off);
      if (lane >= off) x += y;
    }
    if (lane == 63) wsum[wid] = x;
    __syncthreads();
    if (wid == 0) {
      int s = (lane < 16) ? wsum[lane] : 0;
#pragma unroll
      for (int off = 1; off < 16; off <<= 1) {
        int y = __shfl_up(s, off);
        if (lane >= off) s += y;
      }
      if (lane < 16) wsum[lane] = s;
    }
    __syncthreads();
    const int waveoff = (wid > 0) ? wsum[wid - 1] : 0;
    const int incl = x + waveoff + carrySm;
    if (idx < NN) { rp[idx] = incl - v; cu[idx] = incl - v; }
    __syncthreads();
    if (t == 1023) carrySm = incl;
    __syncthreads();
  }
  if (t == 0) rp[NN] = carrySm;
}

__global__ __launch_bounds__(256) void scat_k(const int* __restrict__ ei0,
                                              const int* __restrict__ ei1,
                                              int* __restrict__ cursor,
                                              int* __restrict__ srcs) {
  const int e = blockIdx.x * 256 + threadIdx.x;
  if (e >= EE) return;
  const int et = blockIdx.y;
  const int* ei = et ? ei1 : ei0;
  const int s = ei[e], d = ei[EE + e];
  const int pos = atomicAdd(&cursor[et * NN + d], 1);
  srcs[et * EE + pos] = s;
}

// ---------------- embed both types: h = x @ Win + bin + te + pos; writes f32 + bf16 mirror
__global__ __launch_bounds__(128) void embed2_k(
    const void* __restrict__ x0, const float* __restrict__ Win0,
    const float* __restrict__ bin0, const float* __restrict__ te0,
    const void* __restrict__ pos0, float* __restrict__ h0, u16* __restrict__ h80,
    const void* __restrict__ x1, const float* __restrict__ Win1,
    const float* __restrict__ bin1, const float* __restrict__ te1,
    const void* __restrict__ pos1, float* __restrict__ h1, u16* __restrict__ h81,
    const int* __restrict__ flag) {
  const int ty = blockIdx.y;
  const void* x = ty ? x1 : x0;
  const float* Win = ty ? Win1 : Win0;
  const float* bin = ty ? bin1 : bin0;
  const float* te = ty ? te1 : te0;
  const void* pos = ty ? pos1 : pos0;
  float* h = ty ? h1 : h0;
  u16* h8 = ty ? h81 : h80;
  __shared__ float Ws[64][128];
  __shared__ float xs[16][64];
  const int f32in = *flag;
  const int j = threadIdx.x;
  const int base = blockIdx.x * 16;
  for (int i = 0; i < 64; ++i) Ws[i][j] = Win[i * 128 + j];
  for (int r = 0; r < 8; ++r) {
    int idx = r * 128 + j;
    int row = idx >> 6, k = idx & 63;
    size_t gi = (size_t)(base + row) * 64 + k;
    xs[row][k] = f32in ? ((const float*)x)[gi] : u2f(((const u16*)x)[gi]);
  }
  __syncthreads();
  float bj = bin[j] + te[j];
  for (int row = 0; row < 16; ++row) {
    size_t gi = (size_t)(base + row) * 128 + j;
    float pv = f32in ? ((const float*)pos)[gi] : u2f(((const u16*)pos)[gi]);
    float acc = bj + pv;
#pragma unroll
    for (int k = 0; k < 64; ++k) acc += xs[row][k] * Ws[k][j];
    h[(size_t)(base + row) * 128 + j] = acc;
    h8[(size_t)(base + row) * 128 + j] = f2b(acc);
  }
}

// ---------------- MFMA GEMM (A bf16), dual-task via blockIdx.z
// MODE 2: kvqs (N=3200): cols<3072 -> Cb bf16 stride 3072; cols>=3072 -> Cf f32 stride 128
// MODE 3: gelu -> Cb bf16 (stride N)
// MODE 4: + add(f32) -> Cf f32 AND Cb bf16 (stride N)
struct MG {
  const u16* A; const u16* WT;
  const float* b0; const float* b1; const float* b2; const float* b3;
  const float* add; float* Cf; u16* Cb;
};

template <int MODE>
__global__ __launch_bounds__(256) void mgemm2_k(MG g0, MG g1, int M, int N, int K) {
  const MG g = blockIdx.z ? g1 : g0;
  __shared__ __align__(16) u16 Asl[128][40];
  __shared__ __align__(16) u16 Bsl[64][40];
  const int t = threadIdx.x;
  const int lane = t & 63, wid = t >> 6;
  const int bm = blockIdx.y * 128, bn = blockIdx.x * 64;
  const int rg = lane >> 4, rr = lane & 15;
  f32x4 acc[2][4];
#pragma unroll
  for (int i = 0; i < 2; ++i)
#pragma unroll
    for (int j = 0; j < 4; ++j) acc[i][j] = (f32x4){0.f, 0.f, 0.f, 0.f};
  const int ar = t >> 1;            // 0..127 A row
  const int ah = (t & 1) << 4;      // 0/16 k-offset (16 bf16 = 2 uint4)
  const int wr = t >> 2;            // 0..63 WT row
  const int wk = (t & 3) << 3;      // 0,8,16,24

  for (int k0 = 0; k0 < K; k0 += 32) {
    const int garow = bm + ar;
    uint4 a0 = {0,0,0,0}, a1 = {0,0,0,0};
    if (garow < M) {
      const u16* ap = g.A + (size_t)garow * K + k0 + ah;
      a0 = *reinterpret_cast<const uint4*>(ap);
      a1 = *reinterpret_cast<const uint4*>(ap + 8);
    }
    *reinterpret_cast<uint4*>(&Asl[ar][ah]) = a0;
    *reinterpret_cast<uint4*>(&Asl[ar][ah + 8]) = a1;
    const uint4 bv = *reinterpret_cast<const uint4*>(g.WT + (size_t)(bn + wr) * K + k0 + wk);
    *reinterpret_cast<uint4*>(&Bsl[wr][wk]) = bv;
    __syncthreads();
    bf16x8 af[2], bfr[4];
#pragma unroll
    for (int mi = 0; mi < 2; ++mi)
      af[mi] = *reinterpret_cast<const bf16x8*>(&Asl[wid * 32 + mi * 16 + rr][rg * 8]);
#pragma unroll
    for (int ni = 0; ni < 4; ++ni)
      bfr[ni] = *reinterpret_cast<const bf16x8*>(&Bsl[ni * 16 + rr][rg * 8]);
#pragma unroll
    for (int mi = 0; mi < 2; ++mi)
#pragma unroll
      for (int ni = 0; ni < 4; ++ni)
        acc[mi][ni] = __builtin_amdgcn_mfma_f32_16x16x32_bf16(af[mi], bfr[ni], acc[mi][ni], 0, 0, 0);
    __syncthreads();
  }
#pragma unroll
  for (int mi = 0; mi < 2; ++mi) {
#pragma unroll
    for (int ni = 0; ni < 4; ++ni) {
      const int col = bn + ni * 16 + rr;
      float bcol;
      if (MODE == 2) {
        const int seg = col >> 10;
        const float* bp = (seg == 0) ? g.b0 : ((seg == 1) ? g.b1 : ((seg == 2) ? g.b2 : g.b3));
        bcol = bp[col & 1023];
      } else {
        bcol = g.b0[col];
      }
#pragma unroll
      for (int r = 0; r < 4; ++r) {
        const int row = bm + wid * 32 + mi * 16 + rg * 4 + r;
        if (row >= M) continue;
        float v = acc[mi][ni][r] + bcol;
        if (MODE == 2) {
          if (col < KVQ) g.Cb[(size_t)row * KVQ + col] = f2b(v);
          else           g.Cf[(size_t)row * HIDD + (col - KVQ)] = v;
        } else if (MODE == 3) {
          v = gelu_f(v);
          g.Cb[(size_t)row * N + col] = f2b(v);
        } else {  // MODE 4
          v += g.add[(size_t)row * N + col];
          g.Cf[(size_t)row * N + col] = v;
          g.Cb[(size_t)row * N + col] = f2b(v);
        }
      }
    }
  }
}

// ---------------- legacy fp32 vector GEMM (Wout hedge only), dual via blockIdx.z
struct VG {
  const float* A; const float* B; const float* bias;
  float* Cf; u16* Cb;
};

__global__ __launch_bounds__(256) void gemm2_k(VG g0, VG g1, const int* __restrict__ oflag,
                                               int M, int N, int K) {
  const VG g = blockIdx.z ? g1 : g0;
  __shared__ __align__(16) float As[16][64];
  __shared__ __align__(16) float Bs[16][64];
  const int t = threadIdx.x;
  const int tx = t & 15, ty = t >> 4;
  const int bm = blockIdx.y * 64, bn = blockIdx.x * 64;
  float c[4][4] = {{0.f}};
  const int am = t >> 2;
  const int ak = (t & 3) << 2;
  const int bk = t >> 4;
  const int bn4 = (t & 15) << 2;
  for (int k0 = 0; k0 < K; k0 += 16) {
    float4 av = make_float4(0.f, 0.f, 0.f, 0.f);
    const int arow = bm + am;
    if (arow < M) av = *reinterpret_cast<const float4*>(g.A + (size_t)arow * K + k0 + ak);
    As[ak + 0][am] = av.x; As[ak + 1][am] = av.y;
    As[ak + 2][am] = av.z; As[ak + 3][am] = av.w;
    float4 bv = *reinterpret_cast<const float4*>(g.B + (size_t)(k0 + bk) * N + bn + bn4);
    Bs[bk][bn4 + 0] = bv.x; Bs[bk][bn4 + 1] = bv.y;
    Bs[bk][bn4 + 2] = bv.z; Bs[bk][bn4 + 3] = bv.w;
    __syncthreads();
#pragma unroll
    for (int kk = 0; kk < 16; ++kk) {
      float4 a = *reinterpret_cast<const float4*>(&As[kk][ty << 2]);
      float4 b = *reinterpret_cast<const float4*>(&Bs[kk][tx << 2]);
      c[0][0] += a.x * b.x; c[0][1] += a.x * b.y; c[0][2] += a.x * b.z; c[0][3] += a.x * b.w;
      c[1][0] += a.y * b.x; c[1][1] += a.y * b.y; c[1][2] += a.y * b.z; c[1][3] += a.y * b.w;
      c[2][0] += a.z * b.x; c[2][1] += a.z * b.y; c[2][2] += a.z * b.z; c[2][3] += a.z * b.w;
      c[3][0] += a.w * b.x; c[3][1] += a.w * b.y; c[3][2] += a.w * b.z; c[3][3] += a.w * b.w;
    }
    __syncthreads();
  }
  const int f32out = *oflag;
#pragma unroll
  for (int i = 0; i < 4; ++i) {
    const int row = bm + (ty << 2) + i;
    if (row >= M) continue;
#pragma unroll
    for (int j = 0; j < 4; ++j) {
      const int col = bn + (tx << 2) + j;
      float v = c[i][j] + g.bias[col];
      if (f32out) g.Cf[(size_t)row * N + col] = v;
      else        g.Cb[(size_t)row * N + col] = f2b(v);
    }
  }
}

// ---------------- fused flash attention, both edge types (y = et), 2-edge unrolled
__global__ __launch_bounds__(256) void attn2_k(
    const u16* __restrict__ kvqJ, const u16* __restrict__ kvqM,
    const int* __restrict__ rowptr, const int* __restrict__ srcs,
    float* __restrict__ aggM, float* __restrict__ aggJ) {
  const int et = blockIdx.y;
  const u16* kvqS = et ? kvqM : kvqJ;
  const u16* kvqD = et ? kvqJ : kvqM;
  const int* rp = rowptr + et * (NN + 1);
  const int* sr = srcs + et * EE;
  float* agg = et ? aggJ : aggM;
  const int d = (blockIdx.x * 256 + threadIdx.x) >> 6;
  const int lane = threadIdx.x & 63;
  const u16* qp = kvqD + (size_t)d * KVQ + 2048 + lane * 16;
  uint4 q0 = *reinterpret_cast<const uint4*>(qp);
  uint4 q1 = *reinterpret_cast<const uint4*>(qp + 8);
  float qf[16];
  {
    u32 w[8] = {q0.x, q0.y, q0.z, q0.w, q1.x, q1.y, q1.z, q1.w};
#pragma unroll
    for (int i = 0; i < 8; ++i) { qf[2*i] = u2f(w[i] & 0xffffu); qf[2*i+1] = u2f(w[i] >> 16); }
  }
  float m = -INFINITY, den = 0.f;
  float acc[16];
#pragma unroll
  for (int i = 0; i < 16; ++i) acc[i] = 0.f;
  const int beg = rp[d], end = rp[d + 1];

  auto dot8 = [&](const uint4& a, const uint4& b) -> float {
    float p = 0.f;
    const u32 w[8] = {a.x, a.y, a.z, a.w, b.x, b.y, b.z, b.w};
#pragma unroll
    for (int i = 0; i < 8; ++i) {
      p += qf[2*i] * u2f(w[i] & 0xffffu);
      p += qf[2*i+1] * u2f(w[i] >> 16);
    }
    return p;
  };
  auto update = [&](float part, const uint4& v0w, const uint4& v1w) {
    part += __shfl_xor(part, 1);
    part += __shfl_xor(part, 2);
    part += __shfl_xor(part, 4);
    const float lg = part * 0.088388347648318447f;  // 1/sqrt(128)
    const float nm = fmaxf(m, lg);
    const float cor = __expf(m - nm);
    const float p = __expf(lg - nm);
    den = den * cor + p;
    const u32 w[8] = {v0w.x, v0w.y, v0w.z, v0w.w, v1w.x, v1w.y, v1w.z, v1w.w};
#pragma unroll
    for (int i = 0; i < 8; ++i) {
      acc[2*i]   = acc[2*i]   * cor + p * u2f(w[i] & 0xffffu);
      acc[2*i+1] = acc[2*i+1] * cor + p * u2f(w[i] >> 16);
    }
    m = nm;
  };

  int idx = beg;
  for (; idx + 2 <= end; idx += 2) {
    const int s0 = sr[idx], s1 = sr[idx + 1];
    const u16* kp0 = kvqS + (size_t)s0 * KVQ + lane * 16;
    const u16* kp1 = kvqS + (size_t)s1 * KVQ + lane * 16;
    const uint4 a0 = *reinterpret_cast<const uint4*>(kp0);
    const uint4 a1 = *reinterpret_cast<const uint4*>(kp0 + 8);
    const uint4 av0 = *reinterpret_cast<const uint4*>(kp0 + 1024);
    const uint4 av1 = *reinterpret_cast<const uint4*>(kp0 + 1024 + 8);
    const uint4 b0 = *reinterpret_cast<const uint4*>(kp1);
    const uint4 b1 = *reinterpret_cast<const uint4*>(kp1 + 8);
    const uint4 bv0 = *reinterpret_cast<const uint4*>(kp1 + 1024);
    const uint4 bv1 = *reinterpret_cast<const uint4*>(kp1 + 1024 + 8);
    const float p0 = dot8(a0, a1);
    const float p1 = dot8(b0, b1);
    update(p0, av0, av1);
    update(p1, bv0, bv1);
  }
  if (idx < end) {
    const int s0 = sr[idx];
    const u16* kp0 = kvqS + (size_t)s0 * KVQ + lane * 16;
    const uint4 a0 = *reinterpret_cast<const uint4*>(kp0);
    const uint4 a1 = *reinterpret_cast<const uint4*>(kp0 + 8);
    const uint4 av0 = *reinterpret_cast<const uint4*>(kp0 + 1024);
    const uint4 av1 = *reinterpret_cast<const uint4*>(kp0 + 1024 + 8);
    update(dot8(a0, a1), av0, av1);
  }

  const float inv = 0.125f / (den + 1e-16f);
  float o[16];
#pragma unroll
  for (int i = 0; i < 16; ++i) {
    float tv = acc[i] * inv;
    tv += __shfl_xor(tv, 8);
    tv += __shfl_xor(tv, 16);
    tv += __shfl_xor(tv, 32);
    o[i] = tv;
  }
  if (lane < 8) {
    float* op = agg + (size_t)d * HIDD + lane * 16;
    *reinterpret_cast<float4*>(op + 0)  = make_float4(o[0],  o[1],  o[2],  o[3]);
    *reinterpret_cast<float4*>(op + 4)  = make_float4(o[4],  o[5],  o[6],  o[7]);
    *reinterpret_cast<float4*>(op + 8)  = make_float4(o[8],  o[9],  o[10], o[11]);
    *reinterpret_cast<float4*>(op + 12) = make_float4(o[12], o[13], o[14], o[15]);
  }
}

// ---------------- fused beta gate + LayerNorm(h + new); writes f32 + bf16 mirror
struct BL {
  const float* agg; const float* xr; const float* Wb;
  const float* h; const float* g; const float* b; float* r; u16* r8;
};

__global__ __launch_bounds__(256) void betaln2_k(BL p0, BL p1) {
  const BL p = blockIdx.y ? p1 : p0;
  const int n = (blockIdx.x * 256 + threadIdx.x) >> 6;
  const int lane = threadIdx.x & 63;
  const float o0 = p.agg[(size_t)n * HIDD + lane], o1 = p.agg[(size_t)n * HIDD + 64 + lane];
  const float x0 = p.xr[(size_t)n * HIDD + lane], x1 = p.xr[(size_t)n * HIDD + 64 + lane];
  float s = o0 * p.Wb[lane] + o1 * p.Wb[64 + lane]
          + x0 * p.Wb[128 + lane] + x1 * p.Wb[192 + lane]
          + (o0 - x0) * p.Wb[256 + lane] + (o1 - x1) * p.Wb[320 + lane];
#pragma unroll
  for (int mask = 1; mask < 64; mask <<= 1) s += __shfl_xor(s, mask);
  const float beta = 1.f / (1.f + expf(-s));
  const float n0 = beta * x0 + (1.f - beta) * o0;
  const float n1 = beta * x1 + (1.f - beta) * o1;
  const float v0 = p.h[(size_t)n * HIDD + lane] + n0;
  const float v1 = p.h[(size_t)n * HIDD + 64 + lane] + n1;
  float sm = v0 + v1;
#pragma unroll
  for (int mask = 1; mask < 64; mask <<= 1) sm += __shfl_xor(sm, mask);
  const float mu = sm * (1.f / 128.f);
  const float d0 = v0 - mu, d1 = v1 - mu;
  float vs = d0 * d0 + d1 * d1;
#pragma unroll
  for (int mask = 1; mask < 64; mask <<= 1) vs += __shfl_xor(vs, mask);
  const float rstd = rsqrtf(vs * (1.f / 128.f) + 1e-5f);
  const float r0 = d0 * rstd * p.g[lane] + p.b[lane];
  const float r1 = d1 * rstd * p.g[64 + lane] + p.b[64 + lane];
  p.r[(size_t)n * HIDD + lane]      = r0;
  p.r[(size_t)n * HIDD + 64 + lane] = r1;
  p.r8[(size_t)n * HIDD + lane]      = f2b(r0);
  p.r8[(size_t)n * HIDD + 64 + lane] = f2b(r1);
}

extern "C" void kernel_launch(void* const* d_in, const int* in_sizes, int n_in,
                              void* d_out, int out_size, void* d_ws, size_t ws_size,
                              hipStream_t stream) {
  char* w = (char*)d_ws;
  auto carve = [&](size_t bytes) { void* p = (void*)w; w += (bytes + 255) & ~(size_t)255; return p; };
  float* h_b[2];  h_b[0] = (float*)carve((size_t)NN * HIDD * 4); h_b[1] = (float*)carve((size_t)NN * HIDD * 4);
  u16* h8_b[2];   h8_b[0] = (u16*)carve((size_t)NN * HIDD * 2);  h8_b[1] = (u16*)carve((size_t)NN * HIDD * 2);
  float* rb_b[2]; rb_b[0] = (float*)carve((size_t)NN * HIDD * 4); rb_b[1] = (float*)carve((size_t)NN * HIDD * 4);
  u16* rb8_b[2];  rb8_b[0] = (u16*)carve((size_t)NN * HIDD * 2);  rb8_b[1] = (u16*)carve((size_t)NN * HIDD * 2);
  float* xr_b[2]; xr_b[0] = (float*)carve((size_t)NN * HIDD * 4); xr_b[1] = (float*)carve((size_t)NN * HIDD * 4);
  float* ag_b[2]; ag_b[0] = (float*)carve((size_t)NN * HIDD * 4); ag_b[1] = (float*)carve((size_t)NN * HIDD * 4);
  u16* kvqJ = (u16*)carve((size_t)NN * KVQ * 2);
  u16* kvqM = (u16*)carve((size_t)NN * KVQ * 2);
  u16* mid8_b[2] = {kvqJ, kvqM};  // alias: FFN mid (bf16) after attn done
  int* histb  = (int*)carve(2 * NN * 4);
  int* rowptr = (int*)carve(2 * (NN + 1) * 4);
  int* cursor = (int*)carve(2 * NN * 4);
  int* srcsb  = (int*)carve(2 * EE * 4);
  int* flagp  = (int*)carve(256);
  // FIX(round 8): conversion table is 2*26752 (node params incl Wout) + 2*7168 (edge
  // Wb/bq/bk/bv/bs) = 67840 floats. Previous 40704 under-allocated and convert_k
  // overflowed 108KB into wtp, trashing Wout/Wb/edge-biases.
  const int totCvt = 2 * 26752 + 2 * 7168;  // 67840
  float* wf = (float*)carve((size_t)totCvt * 4);
  u16* wtp = (u16*)carve((size_t)(4 * KVQS * HIDD + 8 * HIDD * FFD) * 2);

  // ---- f32 conversion table (small tensors) ----
  CvtArgs ca; int nc = 0; int cum = 0;
  auto addc = [&](int inIdx, int n) -> float* {
    ca.src[nc] = d_in[inIdx]; ca.cnt[nc] = n; float* p = wf + cum; cum += n; ++nc; return p;
  };
  const float *WinF[2], *binF[2], *teF[2], *lngF[2], *lnbF[2], *b1F[2], *b2F[2], *WoutF[2], *boutF[2];
  const void* x_p[2]; const void* pos_p[2];
  for (int t = 0; t < 2; ++t) {
    const int o = t * 13;
    x_p[t] = d_in[o + 0];
    WinF[t] = addc(o + 1, 64 * HIDD);
    binF[t] = addc(o + 2, HIDD);
    pos_p[t] = d_in[o + 3];
    teF[t]  = addc(o + 4, HIDD);
    lngF[t] = addc(o + 5, 2 * HIDD);
    lnbF[t] = addc(o + 6, 2 * HIDD);
    b1F[t]  = addc(o + 8, 2 * FFD);
    b2F[t]  = addc(o + 10, 2 * HIDD);
    WoutF[t] = addc(o + 11, HIDD * HIDD);
    boutF[t] = addc(o + 12, HIDD);
  }
  const float *WbF[2], *bqF[2], *bkF[2], *bvF[2], *bsF[2];
  const int* ei_e[2];
  for (int et = 0; et < 2; ++et) {
    const int o = 26 + et * 10;
    WbF[et] = addc(o + 4, 2 * 384);
    bqF[et] = addc(o + 5, 2 * INNERD);
    bkF[et] = addc(o + 6, 2 * INNERD);
    bvF[et] = addc(o + 7, 2 * INNERD);
    bsF[et] = addc(o + 8, 2 * HIDD);
    ei_e[et] = (const int*)d_in[o + 9];
  }
  ca.ntot = cum;  // == 67840 == totCvt

  // ---- transpose table: per (et,l) concat [Wk_et|Wv_et|Wq_OTHER|Ws_OTHER] -> [3200][128]
  TTab tt; int ntt = 0; u16* tcur = wtp;
  auto addT = [&](const void* s, long off, int K, int N, u16* dst) {
    tt.m[ntt] = {s, off, dst, K, N}; ++ntt;
  };
  u16* kvqWT[2][2];
  for (int et = 0; et < 2; ++et) {
    const int o  = 26 + et * 10;
    const int oq = 26 + (1 - et) * 10;  // OTHER edge type (Q, Ws weights)
    for (int l = 0; l < 2; ++l) {
      u16* base = tcur; tcur += (size_t)KVQS * HIDD;
      kvqWT[et][l] = base;
      addT(d_in[o + 1],  (long)l * HIDD * INNERD, HIDD, INNERD, base);
      addT(d_in[o + 2],  (long)l * HIDD * INNERD, HIDD, INNERD, base + 1024 * HIDD);
      addT(d_in[oq + 0], (long)l * HIDD * INNERD, HIDD, INNERD, base + 2048 * HIDD);
      addT(d_in[oq + 3], (long)l * HIDD * HIDD,   HIDD, HIDD,   base + 3072 * HIDD);
    }
  }
  u16 *W1T[2][2], *W2T[2][2];
  for (int t = 0; t < 2; ++t) {
    const int o = t * 13;
    for (int l = 0; l < 2; ++l) {
      W1T[t][l] = tcur; addT(d_in[o + 7], (long)l * HIDD * FFD, HIDD, FFD, tcur); tcur += (size_t)HIDD * FFD;
      W2T[t][l] = tcur; addT(d_in[o + 9], (long)l * FFD * HIDD, FFD, HIDD, tcur); tcur += (size_t)FFD * HIDD;
    }
  }

  const dim3 blk(256);
  const int MB64 = (NN + 63) / 64;    // 157
  const int MB128 = (NN + 127) / 128; // 79

  // ---- prep ----
  detect_k<<<1, 64, 0, stream>>>((const u32*)d_in[0], flagp);
  convert_k<<<(cum + 255) / 256, blk, 0, stream>>>(ca, flagp, wf);
  transT_k<<<dim3(32, 16, 24), dim3(32, 8), 0, stream>>>(tt, flagp);
  hipMemsetAsync(histb, 0, 2 * NN * 4, stream);
  hist_k<<<dim3((EE + 255) / 256, 2), blk, 0, stream>>>(ei_e[0], ei_e[1], histb);
  scan2_k<<<2, 1024, 0, stream>>>(histb, rowptr, cursor);
  scat_k<<<dim3((EE + 255) / 256, 2), blk, 0, stream>>>(ei_e[0], ei_e[1], cursor, srcsb);

  // ---- embed (both types, f32 + bf16) ----
  embed2_k<<<dim3(NN / 16, 2), 128, 0, stream>>>(
      x_p[0], WinF[0], binF[0], teF[0], pos_p[0], h_b[0], h8_b[0],
      x_p[1], WinF[1], binF[1], teF[1], pos_p[1], h_b[1], h8_b[1], flagp);

  for (int l = 0; l < 2; ++l) {
    // kvq+S projections, both types: A=h8_j -> [K_jm|V_jm|Q_mj|S_mj] (xr_j); A=h8_m -> ... (xr_m)
    MG gj = {h8_b[0], kvqWT[0][l], bkF[0] + l * INNERD, bvF[0] + l * INNERD,
             bqF[1] + l * INNERD, bsF[1] + l * HIDD, nullptr, xr_b[0], kvqJ};
    MG gm = {h8_b[1], kvqWT[1][l], bkF[1] + l * INNERD, bvF[1] + l * INNERD,
             bqF[0] + l * INNERD, bsF[0] + l * HIDD, nullptr, xr_b[1], kvqM};
    mgemm2_k<2><<<dim3(KVQS / 64, MB128, 2), blk, 0, stream>>>(gj, gm, NN, KVQS, HIDD);
    // attention, both edge types
    attn2_k<<<dim3(NN / 4, 2), blk, 0, stream>>>(kvqJ, kvqM, rowptr, srcsb, ag_b[1], ag_b[0]);
    // beta gate + LN, both node types
    BL p0 = {ag_b[1], xr_b[1], WbF[0] + l * 384, h_b[1],
             lngF[1] + l * HIDD, lnbF[1] + l * HIDD, rb_b[1], rb8_b[1]};
    BL p1 = {ag_b[0], xr_b[0], WbF[1] + l * 384, h_b[0],
             lngF[0] + l * HIDD, lnbF[0] + l * HIDD, rb_b[0], rb8_b[0]};
    betaln2_k<<<dim3(NN / 4, 2), blk, 0, stream>>>(p0, p1);
    // FFN W1 (gelu -> bf16 mid), both types
    MG w1j = {rb8_b[0], W1T[0][l], b1F[0] + l * FFD, nullptr, nullptr, nullptr,
              nullptr, nullptr, mid8_b[0]};
    MG w1m = {rb8_b[1], W1T[1][l], b1F[1] + l * FFD, nullptr, nullptr, nullptr,
              nullptr, nullptr, mid8_b[1]};
    mgemm2_k<3><<<dim3(FFD / 64, MB128, 2), blk, 0, stream>>>(w1j, w1m, NN, FFD, HIDD);
    // FFN W2 (+residual rb) -> h f32 + h8 bf16, both types
    MG w2j = {mid8_b[0], W2T[0][l], b2F[0] + l * HIDD, nullptr, nullptr, nullptr,
              rb_b[0], h_b[0], h8_b[0]};
    MG w2m = {mid8_b[1], W2T[1][l], b2F[1] + l * HIDD, nullptr, nullptr, nullptr,
              rb_b[1], h_b[1], h8_b[1]};
    mgemm2_k<4><<<dim3(HIDD / 64, MB128, 2), blk, 0, stream>>>(w2j, w2m, NN, HIDD, FFD);
  }
  // output projections (fp32 hedge, runtime dtype), both types
  VG o0 = {h_b[0], WoutF[0], boutF[0], (float*)d_out, (u16*)d_out};
  VG o1 = {h_b[1], WoutF[1], boutF[1],
           (float*)d_out + (size_t)NN * HIDD, (u16*)d_out + (size_t)NN * HIDD};
  gemm2_k<<<dim3(HIDD / 64, MB64, 2), blk, 0, stream>>>(o0, o1, flagp, NN, HIDD, HIDD);
}

// Round 10
// 461.099 us; speedup vs baseline: 2.5939x; 1.0133x over previous
//
#include <hip/hip_runtime.h>
#include <hip/hip_bf16.h>

#define NN 10000
#define EE 60000
#define HIDD 128
#define NH 8
#define INNERD 1024
#define FFD 512
#define KVQ 3072
#define KVQS 3200

using u16 = unsigned short;
using u32 = unsigned int;

typedef __bf16 bf16x8 __attribute__((ext_vector_type(8)));
typedef float f32x4 __attribute__((ext_vector_type(4)));

__device__ __forceinline__ float u2f(u32 u) { return __uint_as_float(u << 16); }
__device__ __forceinline__ u16 f2b(float f) {  // RNE
  u32 x = __float_as_uint(f);
  return (u16)((x + 0x7fffu + ((x >> 16) & 1u)) >> 16);
}
__device__ __forceinline__ float gelu_f(float x) {
  return 0.5f * x * (1.0f + erff(x * 0.70710678118654752f));
}

// ---------------- dtype detect (runtime hedge, flag=1 means f32 inputs)
__global__ void detect_k(const u32* __restrict__ xw, int* __restrict__ flag) {
  if (threadIdx.x == 0 && blockIdx.x == 0) {
    int wild = 0;
    for (int i = 0; i < 256; ++i) {
      float v = u2f(xw[i] & 0xffffu);
      if (!(fabsf(v) < 1e4f)) ++wild;
    }
    *flag = (wild > 16) ? 1 : 0;
  }
}

#define NCVT 30
struct CvtArgs { const void* src[NCVT]; int cnt[NCVT]; int ntot; };

__global__ __launch_bounds__(256) void convert_k(CvtArgs a, const int* __restrict__ flag,
                                                 float* __restrict__ dst) {
  const int i = blockIdx.x * 256 + threadIdx.x;
  if (i >= a.ntot) return;
  int t = 0, off = i;
  while (off >= a.cnt[t]) { off -= a.cnt[t]; ++t; }
  const float v = (*flag) ? ((const float*)a.src[t])[off]
                          : u2f(((const u16*)a.src[t])[off]);
  dst[i] = v;
}

// ---------------- batched weight transpose: W[K][N] -> WT bf16 [N][K]
struct TT { const void* s; long off; u16* d; int K; int N; };
struct TTab { TT m[28]; };

__global__ __launch_bounds__(256) void transT_k(TTab tt, const int* __restrict__ flag) {
  const TT m = tt.m[blockIdx.z];
  const int n0 = blockIdx.x * 32, k0 = blockIdx.y * 32;
  if (n0 >= m.N || k0 >= m.K) return;
  __shared__ float tile[32][33];
  const int c = threadIdx.x;
  const int f32in = *flag;
  for (int i = threadIdx.y; i < 32; i += 8) {
    const long gi = m.off + (long)(k0 + i) * m.N + n0 + c;
    tile[i][c] = f32in ? ((const float*)m.s)[gi] : u2f(((const u16*)m.s)[gi]);
  }
  __syncthreads();
  for (int i = threadIdx.y; i < 32; i += 8)
    m.d[(size_t)(n0 + i) * m.K + k0 + c] = f2b(tile[c][i]);
}

// ---------------- CSR build
__global__ __launch_bounds__(256) void hist_k(const int* __restrict__ ei0,
                                              const int* __restrict__ ei1,
                                              int* __restrict__ hist) {
  const int e = blockIdx.x * 256 + threadIdx.x;
  if (e >= EE) return;
  const int et = blockIdx.y;
  const int* ei = et ? ei1 : ei0;
  atomicAdd(&hist[et * NN + ei[EE + e]], 1);
}

__global__ __launch_bounds__(1024) void scan2_k(const int* __restrict__ hist,
                                                int* __restrict__ rowptr,
                                                int* __restrict__ cursor) {
  const int et = blockIdx.x;
  const int* h = hist + et * NN;
  int* rp = rowptr + et * (NN + 1);
  int* cu = cursor + et * NN;
  __shared__ int wsum[16];
  __shared__ int carrySm;
  const int t = threadIdx.x, lane = t & 63, wid = t >> 6;
  if (t == 0) carrySm = 0;
  __syncthreads();
  for (int base = 0; base < NN; base += 1024) {
    const int idx = base + t;
    const int v = (idx < NN) ? h[idx] : 0;
    int x = v;
#pragma unroll
    for (int off = 1; off < 64; off <<= 1) {
      int y = __shfl_up(x, off);
      if (lane >= off) x += y;
    }
    if (lane == 63) wsum[wid] = x;
    __syncthreads();
    if (wid == 0) {
      int s = (lane < 16) ? wsum[lane] : 0;
#pragma unroll
      for (int off = 1; off < 16; off <<= 1) {
        int y = __shfl_up(s, off);
        if (lane >= off) s += y;
      }
      if (lane < 16) wsum[lane] = s;
    }
    __syncthreads();
    const int waveoff = (wid > 0) ? wsum[wid - 1] : 0;
    const int incl = x + waveoff + carrySm;
    if (idx < NN) { rp[idx] = incl - v; cu[idx] = incl - v; }
    __syncthreads();
    if (t == 1023) carrySm = incl;
    __syncthreads();
  }
  if (t == 0) rp[NN] = carrySm;
}

__global__ __launch_bounds__(256) void scat_k(const int* __restrict__ ei0,
                                              const int* __restrict__ ei1,
                                              int* __restrict__ cursor,
                                              int* __restrict__ srcs) {
  const int e = blockIdx.x * 256 + threadIdx.x;
  if (e >= EE) return;
  const int et = blockIdx.y;
  const int* ei = et ? ei1 : ei0;
  const int s = ei[e], d = ei[EE + e];
  const int pos = atomicAdd(&cursor[et * NN + d], 1);
  srcs[et * EE + pos] = s;
}

// ---------------- embed both types: h = x @ Win + bin + te + pos; writes f32 + bf16 mirror
__global__ __launch_bounds__(128) void embed2_k(
    const void* __restrict__ x0, const float* __restrict__ Win0,
    const float* __restrict__ bin0, const float* __restrict__ te0,
    const void* __restrict__ pos0, float* __restrict__ h0, u16* __restrict__ h80,
    const void* __restrict__ x1, const float* __restrict__ Win1,
    const float* __restrict__ bin1, const float* __restrict__ te1,
    const void* __restrict__ pos1, float* __restrict__ h1, u16* __restrict__ h81,
    const int* __restrict__ flag) {
  const int ty = blockIdx.y;
  const void* x = ty ? x1 : x0;
  const float* Win = ty ? Win1 : Win0;
  const float* bin = ty ? bin1 : bin0;
  const float* te = ty ? te1 : te0;
  const void* pos = ty ? pos1 : pos0;
  float* h = ty ? h1 : h0;
  u16* h8 = ty ? h81 : h80;
  __shared__ float Ws[64][128];
  __shared__ float xs[16][64];
  const int f32in = *flag;
  const int j = threadIdx.x;
  const int base = blockIdx.x * 16;
  for (int i = 0; i < 64; ++i) Ws[i][j] = Win[i * 128 + j];
  for (int r = 0; r < 8; ++r) {
    int idx = r * 128 + j;
    int row = idx >> 6, k = idx & 63;
    size_t gi = (size_t)(base + row) * 64 + k;
    xs[row][k] = f32in ? ((const float*)x)[gi] : u2f(((const u16*)x)[gi]);
  }
  __syncthreads();
  float bj = bin[j] + te[j];
  for (int row = 0; row < 16; ++row) {
    size_t gi = (size_t)(base + row) * 128 + j;
    float pv = f32in ? ((const float*)pos)[gi] : u2f(((const u16*)pos)[gi]);
    float acc = bj + pv;
#pragma unroll
    for (int k = 0; k < 64; ++k) acc += xs[row][k] * Ws[k][j];
    h[(size_t)(base + row) * 128 + j] = acc;
    h8[(size_t)(base + row) * 128 + j] = f2b(acc);
  }
}

// ---------------- MFMA GEMM (A bf16), dual-task via blockIdx.z
// MODE 2: kvqs (N=3200): cols<3072 -> Cb bf16 stride 3072; cols>=3072 -> Cf f32 stride 128
// MODE 3: gelu -> Cb bf16 (stride N)
// MODE 4: + add(f32) -> Cf f32 AND Cb bf16 (stride N)
struct MG {
  const u16* A; const u16* WT;
  const float* b0; const float* b1; const float* b2; const float* b3;
  const float* add; float* Cf; u16* Cb;
};

template <int MODE>
__global__ __launch_bounds__(256) void mgemm2_k(MG g0, MG g1, int M, int N, int K) {
  const MG g = blockIdx.z ? g1 : g0;
  __shared__ __align__(16) u16 Asl[128][40];
  __shared__ __align__(16) u16 Bsl[64][40];
  const int t = threadIdx.x;
  const int lane = t & 63, wid = t >> 6;
  const int bm = blockIdx.y * 128, bn = blockIdx.x * 64;
  const int rg = lane >> 4, rr = lane & 15;
  f32x4 acc[2][4];
#pragma unroll
  for (int i = 0; i < 2; ++i)
#pragma unroll
    for (int j = 0; j < 4; ++j) acc[i][j] = (f32x4){0.f, 0.f, 0.f, 0.f};
  const int ar = t >> 1;
  const int ah = (t & 1) << 4;
  const int wr = t >> 2;
  const int wk = (t & 3) << 3;

  for (int k0 = 0; k0 < K; k0 += 32) {
    const int garow = bm + ar;
    uint4 a0 = {0,0,0,0}, a1 = {0,0,0,0};
    if (garow < M) {
      const u16* ap = g.A + (size_t)garow * K + k0 + ah;
      a0 = *reinterpret_cast<const uint4*>(ap);
      a1 = *reinterpret_cast<const uint4*>(ap + 8);
    }
    *reinterpret_cast<uint4*>(&Asl[ar][ah]) = a0;
    *reinterpret_cast<uint4*>(&Asl[ar][ah + 8]) = a1;
    const uint4 bv = *reinterpret_cast<const uint4*>(g.WT + (size_t)(bn + wr) * K + k0 + wk);
    *reinterpret_cast<uint4*>(&Bsl[wr][wk]) = bv;
    __syncthreads();
    bf16x8 af[2], bfr[4];
#pragma unroll
    for (int mi = 0; mi < 2; ++mi)
      af[mi] = *reinterpret_cast<const bf16x8*>(&Asl[wid * 32 + mi * 16 + rr][rg * 8]);
#pragma unroll
    for (int ni = 0; ni < 4; ++ni)
      bfr[ni] = *reinterpret_cast<const bf16x8*>(&Bsl[ni * 16 + rr][rg * 8]);
#pragma unroll
    for (int mi = 0; mi < 2; ++mi)
#pragma unroll
      for (int ni = 0; ni < 4; ++ni)
        acc[mi][ni] = __builtin_amdgcn_mfma_f32_16x16x32_bf16(af[mi], bfr[ni], acc[mi][ni], 0, 0, 0);
    __syncthreads();
  }
#pragma unroll
  for (int mi = 0; mi < 2; ++mi) {
#pragma unroll
    for (int ni = 0; ni < 4; ++ni) {
      const int col = bn + ni * 16 + rr;
      float bcol;
      if (MODE == 2) {
        const int seg = col >> 10;
        const float* bp = (seg == 0) ? g.b0 : ((seg == 1) ? g.b1 : ((seg == 2) ? g.b2 : g.b3));
        bcol = bp[col & 1023];
      } else {
        bcol = g.b0[col];
      }
#pragma unroll
      for (int r = 0; r < 4; ++r) {
        const int row = bm + wid * 32 + mi * 16 + rg * 4 + r;
        if (row >= M) continue;
        float v = acc[mi][ni][r] + bcol;
        if (MODE == 2) {
          if (col < KVQ) g.Cb[(size_t)row * KVQ + col] = f2b(v);
          else           g.Cf[(size_t)row * HIDD + (col - KVQ)] = v;
        } else if (MODE == 3) {
          v = gelu_f(v);
          g.Cb[(size_t)row * N + col] = f2b(v);
        } else {  // MODE 4
          v += g.add[(size_t)row * N + col];
          g.Cf[(size_t)row * N + col] = v;
          g.Cb[(size_t)row * N + col] = f2b(v);
        }
      }
    }
  }
}

// ---------------- legacy fp32 vector GEMM (Wout hedge only), dual via blockIdx.z
struct VG {
  const float* A; const float* B; const float* bias;
  float* Cf; u16* Cb;
};

__global__ __launch_bounds__(256) void gemm2_k(VG g0, VG g1, const int* __restrict__ oflag,
                                               int M, int N, int K) {
  const VG g = blockIdx.z ? g1 : g0;
  __shared__ __align__(16) float As[16][64];
  __shared__ __align__(16) float Bs[16][64];
  const int t = threadIdx.x;
  const int tx = t & 15, ty = t >> 4;
  const int bm = blockIdx.y * 64, bn = blockIdx.x * 64;
  float c[4][4] = {{0.f}};
  const int am = t >> 2;
  const int ak = (t & 3) << 2;
  const int bk = t >> 4;
  const int bn4 = (t & 15) << 2;
  for (int k0 = 0; k0 < K; k0 += 16) {
    float4 av = make_float4(0.f, 0.f, 0.f, 0.f);
    const int arow = bm + am;
    if (arow < M) av = *reinterpret_cast<const float4*>(g.A + (size_t)arow * K + k0 + ak);
    As[ak + 0][am] = av.x; As[ak + 1][am] = av.y;
    As[ak + 2][am] = av.z; As[ak + 3][am] = av.w;
    float4 bv = *reinterpret_cast<const float4*>(g.B + (size_t)(k0 + bk) * N + bn + bn4);
    Bs[bk][bn4 + 0] = bv.x; Bs[bk][bn4 + 1] = bv.y;
    Bs[bk][bn4 + 2] = bv.z; Bs[bk][bn4 + 3] = bv.w;
    __syncthreads();
#pragma unroll
    for (int kk = 0; kk < 16; ++kk) {
      float4 a = *reinterpret_cast<const float4*>(&As[kk][ty << 2]);
      float4 b = *reinterpret_cast<const float4*>(&Bs[kk][tx << 2]);
      c[0][0] += a.x * b.x; c[0][1] += a.x * b.y; c[0][2] += a.x * b.z; c[0][3] += a.x * b.w;
      c[1][0] += a.y * b.x; c[1][1] += a.y * b.y; c[1][2] += a.y * b.z; c[1][3] += a.y * b.w;
      c[2][0] += a.z * b.x; c[2][1] += a.z * b.y; c[2][2] += a.z * b.z; c[2][3] += a.z * b.w;
      c[3][0] += a.w * b.x; c[3][1] += a.w * b.y; c[3][2] += a.w * b.z; c[3][3] += a.w * b.w;
    }
    __syncthreads();
  }
  const int f32out = *oflag;
#pragma unroll
  for (int i = 0; i < 4; ++i) {
    const int row = bm + (ty << 2) + i;
    if (row >= M) continue;
#pragma unroll
    for (int j = 0; j < 4; ++j) {
      const int col = bn + (tx << 2) + j;
      float v = c[i][j] + g.bias[col];
      if (f32out) g.Cf[(size_t)row * N + col] = v;
      else        g.Cb[(size_t)row * N + col] = f2b(v);
    }
  }
}

// ---------------- fused flash attention + beta gate + LayerNorm, both edge types (y = et)
// Epilogue params per edge type (dst node type's tensors)
struct ABL {
  const float* Wb; const float* hrow; const float* lgam; const float* lbet;
  const float* xr; float* r; u16* r8;
};

__global__ __launch_bounds__(256) void attnbl2_k(
    const u16* __restrict__ kvqJ, const u16* __restrict__ kvqM,
    const int* __restrict__ rowptr, const int* __restrict__ srcs,
    ABL bl0, ABL bl1) {
  const int et = blockIdx.y;
  const u16* kvqS = et ? kvqM : kvqJ;
  const u16* kvqD = et ? kvqJ : kvqM;
  const int* rp = rowptr + et * (NN + 1);
  const int* sr = srcs + et * EE;
  const ABL pb = et ? bl1 : bl0;
  const int d = (blockIdx.x * 256 + threadIdx.x) >> 6;
  const int lane = threadIdx.x & 63;
  const u16* qp = kvqD + (size_t)d * KVQ + 2048 + lane * 16;
  uint4 q0 = *reinterpret_cast<const uint4*>(qp);
  uint4 q1 = *reinterpret_cast<const uint4*>(qp + 8);
  float qf[16];
  {
    u32 w[8] = {q0.x, q0.y, q0.z, q0.w, q1.x, q1.y, q1.z, q1.w};
#pragma unroll
    for (int i = 0; i < 8; ++i) { qf[2*i] = u2f(w[i] & 0xffffu); qf[2*i+1] = u2f(w[i] >> 16); }
  }
  float m = -INFINITY, den = 0.f;
  float acc[16];
#pragma unroll
  for (int i = 0; i < 16; ++i) acc[i] = 0.f;
  const int beg = rp[d], end = rp[d + 1];

  auto dot8 = [&](const uint4& a, const uint4& b) -> float {
    float p = 0.f;
    const u32 w[8] = {a.x, a.y, a.z, a.w, b.x, b.y, b.z, b.w};
#pragma unroll
    for (int i = 0; i < 8; ++i) {
      p += qf[2*i] * u2f(w[i] & 0xffffu);
      p += qf[2*i+1] * u2f(w[i] >> 16);
    }
    return p;
  };
  auto wred = [&](float p) -> float {
    p += __shfl_xor(p, 1);
    p += __shfl_xor(p, 2);
    p += __shfl_xor(p, 4);
    return p * 0.088388347648318447f;  // 1/sqrt(128)
  };

  int idx = beg;
  for (; idx + 2 <= end; idx += 2) {
    const int s0 = sr[idx], s1 = sr[idx + 1];
    const u16* kp0 = kvqS + (size_t)s0 * KVQ + lane * 16;
    const u16* kp1 = kvqS + (size_t)s1 * KVQ + lane * 16;
    const uint4 a0 = *reinterpret_cast<const uint4*>(kp0);
    const uint4 a1 = *reinterpret_cast<const uint4*>(kp0 + 8);
    const uint4 av0 = *reinterpret_cast<const uint4*>(kp0 + 1024);
    const uint4 av1 = *reinterpret_cast<const uint4*>(kp0 + 1024 + 8);
    const uint4 b0 = *reinterpret_cast<const uint4*>(kp1);
    const uint4 b1 = *reinterpret_cast<const uint4*>(kp1 + 8);
    const uint4 bv0 = *reinterpret_cast<const uint4*>(kp1 + 1024);
    const uint4 bv1 = *reinterpret_cast<const uint4*>(kp1 + 1024 + 8);
    const float lg0 = wred(dot8(a0, a1));
    const float lg1 = wred(dot8(b0, b1));
    // batched 2-edge online-softmax update (one rescale per pair)
    const float nm = fmaxf(m, fmaxf(lg0, lg1));
    const float cor = __expf(m - nm);
    const float p0 = __expf(lg0 - nm);
    const float p1 = __expf(lg1 - nm);
    den = den * cor + p0 + p1;
    const u32 wa[8] = {av0.x, av0.y, av0.z, av0.w, av1.x, av1.y, av1.z, av1.w};
    const u32 wb[8] = {bv0.x, bv0.y, bv0.z, bv0.w, bv1.x, bv1.y, bv1.z, bv1.w};
#pragma unroll
    for (int i = 0; i < 8; ++i) {
      acc[2*i]   = (acc[2*i]   * cor + p0 * u2f(wa[i] & 0xffffu)) + p1 * u2f(wb[i] & 0xffffu);
      acc[2*i+1] = (acc[2*i+1] * cor + p0 * u2f(wa[i] >> 16))     + p1 * u2f(wb[i] >> 16);
    }
    m = nm;
  }
  if (idx < end) {
    const int s0 = sr[idx];
    const u16* kp0 = kvqS + (size_t)s0 * KVQ + lane * 16;
    const uint4 a0 = *reinterpret_cast<const uint4*>(kp0);
    const uint4 a1 = *reinterpret_cast<const uint4*>(kp0 + 8);
    const uint4 av0 = *reinterpret_cast<const uint4*>(kp0 + 1024);
    const uint4 av1 = *reinterpret_cast<const uint4*>(kp0 + 1024 + 8);
    const float lg = wred(dot8(a0, a1));
    const float nm = fmaxf(m, lg);
    const float cor = __expf(m - nm);
    const float p = __expf(lg - nm);
    den = den * cor + p;
    const u32 w[8] = {av0.x, av0.y, av0.z, av0.w, av1.x, av1.y, av1.z, av1.w};
#pragma unroll
    for (int i = 0; i < 8; ++i) {
      acc[2*i]   = acc[2*i]   * cor + p * u2f(w[i] & 0xffffu);
      acc[2*i+1] = acc[2*i+1] * cor + p * u2f(w[i] >> 16);
    }
    m = nm;
  }

  // head mean: o[i] = dim (lane&7)*16+i, replicated across lane octets
  const float inv = 0.125f / (den + 1e-16f);
  float o[16];
#pragma unroll
  for (int i = 0; i < 16; ++i) {
    float tv = acc[i] * inv;
    tv += __shfl_xor(tv, 8);
    tv += __shfl_xor(tv, 16);
    tv += __shfl_xor(tv, 32);
    o[i] = tv;
  }

  // ---- fused beta gate + LN(h + new) ----
  const int g8 = (lane & 7) * 16;
  float x[16], hd[16];
  {
    const float* xrp = pb.xr + (size_t)d * HIDD + g8;
    const float* hp  = pb.hrow + (size_t)d * HIDD + g8;
#pragma unroll
    for (int i = 0; i < 16; i += 4) {
      const float4 xv = *reinterpret_cast<const float4*>(xrp + i);
      const float4 hv = *reinterpret_cast<const float4*>(hp + i);
      x[i] = xv.x; x[i+1] = xv.y; x[i+2] = xv.z; x[i+3] = xv.w;
      hd[i] = hv.x; hd[i+1] = hv.y; hd[i+2] = hv.z; hd[i+3] = hv.w;
    }
  }
  float s = 0.f;
#pragma unroll
  for (int i = 0; i < 16; ++i) {
    s += o[i] * pb.Wb[g8 + i] + x[i] * pb.Wb[128 + g8 + i]
       + (o[i] - x[i]) * pb.Wb[256 + g8 + i];
  }
  s += __shfl_xor(s, 1);
  s += __shfl_xor(s, 2);
  s += __shfl_xor(s, 4);
  const float beta = 1.f / (1.f + expf(-s));
  float v[16];
  float psum = 0.f;
#pragma unroll
  for (int i = 0; i < 16; ++i) {
    v[i] = hd[i] + beta * x[i] + (1.f - beta) * o[i];
    psum += v[i];
  }
  psum += __shfl_xor(psum, 1);
  psum += __shfl_xor(psum, 2);
  psum += __shfl_xor(psum, 4);
  const float mu = psum * (1.f / 128.f);
  float pvar = 0.f;
#pragma unroll
  for (int i = 0; i < 16; ++i) {
    const float dv = v[i] - mu;
    pvar += dv * dv;
  }
  pvar += __shfl_xor(pvar, 1);
  pvar += __shfl_xor(pvar, 2);
  pvar += __shfl_xor(pvar, 4);
  const float rstd = rsqrtf(pvar * (1.f / 128.f) + 1e-5f);
  float r[16];
#pragma unroll
  for (int i = 0; i < 16; ++i)
    r[i] = (v[i] - mu) * rstd * pb.lgam[g8 + i] + pb.lbet[g8 + i];
  if (lane < 8) {
    float* rp_ = pb.r + (size_t)d * HIDD + g8;
#pragma unroll
    for (int i = 0; i < 16; i += 4)
      *reinterpret_cast<float4*>(rp_ + i) = make_float4(r[i], r[i+1], r[i+2], r[i+3]);
    u32 pk[8];
#pragma unroll
    for (int i = 0; i < 8; ++i)
      pk[i] = (u32)f2b(r[2*i]) | ((u32)f2b(r[2*i+1]) << 16);
    uint4* r8p = reinterpret_cast<uint4*>(pb.r8 + (size_t)d * HIDD + g8);
    r8p[0] = (uint4){pk[0], pk[1], pk[2], pk[3]};
    r8p[1] = (uint4){pk[4], pk[5], pk[6], pk[7]};
  }
}

extern "C" void kernel_launch(void* const* d_in, const int* in_sizes, int n_in,
                              void* d_out, int out_size, void* d_ws, size_t ws_size,
                              hipStream_t stream) {
  char* w = (char*)d_ws;
  auto carve = [&](size_t bytes) { void* p = (void*)w; w += (bytes + 255) & ~(size_t)255; return p; };
  float* h_b[2];  h_b[0] = (float*)carve((size_t)NN * HIDD * 4); h_b[1] = (float*)carve((size_t)NN * HIDD * 4);
  u16* h8_b[2];   h8_b[0] = (u16*)carve((size_t)NN * HIDD * 2);  h8_b[1] = (u16*)carve((size_t)NN * HIDD * 2);
  float* rb_b[2]; rb_b[0] = (float*)carve((size_t)NN * HIDD * 4); rb_b[1] = (float*)carve((size_t)NN * HIDD * 4);
  u16* rb8_b[2];  rb8_b[0] = (u16*)carve((size_t)NN * HIDD * 2);  rb8_b[1] = (u16*)carve((size_t)NN * HIDD * 2);
  float* xr_b[2]; xr_b[0] = (float*)carve((size_t)NN * HIDD * 4); xr_b[1] = (float*)carve((size_t)NN * HIDD * 4);
  u16* kvqJ = (u16*)carve((size_t)NN * KVQ * 2);
  u16* kvqM = (u16*)carve((size_t)NN * KVQ * 2);
  u16* mid8_b[2] = {kvqJ, kvqM};  // alias: FFN mid (bf16) after attn done
  int* histb  = (int*)carve(2 * NN * 4);
  int* rowptr = (int*)carve(2 * (NN + 1) * 4);
  int* cursor = (int*)carve(2 * NN * 4);
  int* srcsb  = (int*)carve(2 * EE * 4);
  int* flagp  = (int*)carve(256);
  const int totCvt = 2 * 26752 + 2 * 7168;  // 67840 floats (validated round 9)
  float* wf = (float*)carve((size_t)totCvt * 4);
  u16* wtp = (u16*)carve((size_t)(4 * KVQS * HIDD + 8 * HIDD * FFD) * 2);

  // ---- f32 conversion table (small tensors) ----
  CvtArgs ca; int nc = 0; int cum = 0;
  auto addc = [&](int inIdx, int n) -> float* {
    ca.src[nc] = d_in[inIdx]; ca.cnt[nc] = n; float* p = wf + cum; cum += n; ++nc; return p;
  };
  const float *WinF[2], *binF[2], *teF[2], *lngF[2], *lnbF[2], *b1F[2], *b2F[2], *WoutF[2], *boutF[2];
  const void* x_p[2]; const void* pos_p[2];
  for (int t = 0; t < 2; ++t) {
    const int o = t * 13;
    x_p[t] = d_in[o + 0];
    WinF[t] = addc(o + 1, 64 * HIDD);
    binF[t] = addc(o + 2, HIDD);
    pos_p[t] = d_in[o + 3];
    teF[t]  = addc(o + 4, HIDD);
    lngF[t] = addc(o + 5, 2 * HIDD);
    lnbF[t] = addc(o + 6, 2 * HIDD);
    b1F[t]  = addc(o + 8, 2 * FFD);
    b2F[t]  = addc(o + 10, 2 * HIDD);
    WoutF[t] = addc(o + 11, HIDD * HIDD);
    boutF[t] = addc(o + 12, HIDD);
  }
  const float *WbF[2], *bqF[2], *bkF[2], *bvF[2], *bsF[2];
  const int* ei_e[2];
  for (int et = 0; et < 2; ++et) {
    const int o = 26 + et * 10;
    WbF[et] = addc(o + 4, 2 * 384);
    bqF[et] = addc(o + 5, 2 * INNERD);
    bkF[et] = addc(o + 6, 2 * INNERD);
    bvF[et] = addc(o + 7, 2 * INNERD);
    bsF[et] = addc(o + 8, 2 * HIDD);
    ei_e[et] = (const int*)d_in[o + 9];
  }
  ca.ntot = cum;  // == 67840 == totCvt

  // ---- transpose table: per (et,l) concat [Wk_et|Wv_et|Wq_OTHER|Ws_OTHER] -> [3200][128]
  TTab tt; int ntt = 0; u16* tcur = wtp;
  auto addT = [&](const void* s, long off, int K, int N, u16* dst) {
    tt.m[ntt] = {s, off, dst, K, N}; ++ntt;
  };
  u16* kvqWT[2][2];
  for (int et = 0; et < 2; ++et) {
    const int o  = 26 + et * 10;
    const int oq = 26 + (1 - et) * 10;  // OTHER edge type (Q, Ws weights)
    for (int l = 0; l < 2; ++l) {
      u16* base = tcur; tcur += (size_t)KVQS * HIDD;
      kvqWT[et][l] = base;
      addT(d_in[o + 1],  (long)l * HIDD * INNERD, HIDD, INNERD, base);
      addT(d_in[o + 2],  (long)l * HIDD * INNERD, HIDD, INNERD, base + 1024 * HIDD);
      addT(d_in[oq + 0], (long)l * HIDD * INNERD, HIDD, INNERD, base + 2048 * HIDD);
      addT(d_in[oq + 3], (long)l * HIDD * HIDD,   HIDD, HIDD,   base + 3072 * HIDD);
    }
  }
  u16 *W1T[2][2], *W2T[2][2];
  for (int t = 0; t < 2; ++t) {
    const int o = t * 13;
    for (int l = 0; l < 2; ++l) {
      W1T[t][l] = tcur; addT(d_in[o + 7], (long)l * HIDD * FFD, HIDD, FFD, tcur); tcur += (size_t)HIDD * FFD;
      W2T[t][l] = tcur; addT(d_in[o + 9], (long)l * FFD * HIDD, FFD, HIDD, tcur); tcur += (size_t)FFD * HIDD;
    }
  }

  const dim3 blk(256);
  const int MB64 = (NN + 63) / 64;    // 157
  const int MB128 = (NN + 127) / 128; // 79

  // ---- prep ----
  detect_k<<<1, 64, 0, stream>>>((const u32*)d_in[0], flagp);
  convert_k<<<(cum + 255) / 256, blk, 0, stream>>>(ca, flagp, wf);
  transT_k<<<dim3(32, 16, 24), dim3(32, 8), 0, stream>>>(tt, flagp);
  hipMemsetAsync(histb, 0, 2 * NN * 4, stream);
  hist_k<<<dim3((EE + 255) / 256, 2), blk, 0, stream>>>(ei_e[0], ei_e[1], histb);
  scan2_k<<<2, 1024, 0, stream>>>(histb, rowptr, cursor);
  scat_k<<<dim3((EE + 255) / 256, 2), blk, 0, stream>>>(ei_e[0], ei_e[1], cursor, srcsb);

  // ---- embed (both types, f32 + bf16) ----
  embed2_k<<<dim3(NN / 16, 2), 128, 0, stream>>>(
      x_p[0], WinF[0], binF[0], teF[0], pos_p[0], h_b[0], h8_b[0],
      x_p[1], WinF[1], binF[1], teF[1], pos_p[1], h_b[1], h8_b[1], flagp);

  for (int l = 0; l < 2; ++l) {
    // kvq+S projections: A=h8_j -> [K_jm|V_jm|Q_mj|S_mj] (xr_j); A=h8_m -> ... (xr_m)
    MG gj = {h8_b[0], kvqWT[0][l], bkF[0] + l * INNERD, bvF[0] + l * INNERD,
             bqF[1] + l * INNERD, bsF[1] + l * HIDD, nullptr, xr_b[0], kvqJ};
    MG gm = {h8_b[1], kvqWT[1][l], bkF[1] + l * INNERD, bvF[1] + l * INNERD,
             bqF[0] + l * INNERD, bsF[0] + l * HIDD, nullptr, xr_b[1], kvqM};
    mgemm2_k<2><<<dim3(KVQS / 64, MB128, 2), blk, 0, stream>>>(gj, gm, NN, KVQS, HIDD);
    // attention + beta + LN (fused): y=0 jm->dst mach(type1); y=1 mj->dst job(type0)
    ABL bl0 = {WbF[0] + l * 384, h_b[1], lngF[1] + l * HIDD, lnbF[1] + l * HIDD,
               xr_b[1], rb_b[1], rb8_b[1]};
    ABL bl1 = {WbF[1] + l * 384, h_b[0], lngF[0] + l * HIDD, lnbF[0] + l * HIDD,
               xr_b[0], rb_b[0], rb8_b[0]};
    attnbl2_k<<<dim3(NN / 4, 2), blk, 0, stream>>>(kvqJ, kvqM, rowptr, srcsb, bl0, bl1);
    // FFN W1 (gelu -> bf16 mid), both types
    MG w1j = {rb8_b[0], W1T[0][l], b1F[0] + l * FFD, nullptr, nullptr, nullptr,
              nullptr, nullptr, mid8_b[0]};
    MG w1m = {rb8_b[1], W1T[1][l], b1F[1] + l * FFD, nullptr, nullptr, nullptr,
              nullptr, nullptr, mid8_b[1]};
    mgemm2_k<3><<<dim3(FFD / 64, MB128, 2), blk, 0, stream>>>(w1j, w1m, NN, FFD, HIDD);
    // FFN W2 (+residual rb) -> h f32 + h8 bf16, both types
    MG w2j = {mid8_b[0], W2T[0][l], b2F[0] + l * HIDD, nullptr, nullptr, nullptr,
              rb_b[0], h_b[0], h8_b[0]};
    MG w2m = {mid8_b[1], W2T[1][l], b2F[1] + l * HIDD, nullptr, nullptr, nullptr,
              rb_b[1], h_b[1], h8_b[1]};
    mgemm2_k<4><<<dim3(HIDD / 64, MB128, 2), blk, 0, stream>>>(w2j, w2m, NN, HIDD, FFD);
  }
  // output projections (fp32 hedge, runtime dtype), both types
  VG o0 = {h_b[0], WoutF[0], boutF[0], (float*)d_out, (u16*)d_out};
  VG o1 = {h_b[1], WoutF[1], boutF[1],
           (float*)d_out + (size_t)NN * HIDD, (u16*)d_out + (size_t)NN * HIDD};
  gemm2_k<<<dim3(HIDD / 64, MB64, 2), blk, 0, stream>>>(o0, o1, flagp, NN, HIDD, HIDD);
}